// Round 1
// baseline (556.960 us; speedup 1.0000x reference)
//
#include <hip/hip_runtime.h>
#include <hip/hip_bf16.h>

// Problem constants
#define TSEQ   1024
#define NC     1024          // C
#define MBT    4096          // B*T
#define NEXP   8
#define NHEAD  16
#define DHEAD  64
#define PERM_CAP 10240       // 8192 pairs + 16 groups * 128 pad
#define MAXTILES 96

typedef __attribute__((ext_vector_type(8))) short bf16x8;
typedef __attribute__((ext_vector_type(4))) float f32x4;

static __device__ __forceinline__ unsigned short f2bf(float x){
    union { __hip_bfloat16 h; unsigned short u; } v;
    v.h = __float2bfloat16(x);
    return v.u;
}

// ---------------------------------------------------------------------------
// Gate: logits = x@Wg + noise*softplus(x@Wn); top2; softmax(2) -> epair/wpair
// one wave per token
// ---------------------------------------------------------------------------
__global__ __launch_bounds__(64)
void gate_kernel(const float* __restrict__ x, const float* __restrict__ noise,
                 const float* __restrict__ Wg, const float* __restrict__ Wn,
                 int* __restrict__ epair, float* __restrict__ wpair){
    int t = blockIdx.x;
    int lane = threadIdx.x;
    float ag[8] = {0,0,0,0,0,0,0,0};
    float an[8] = {0,0,0,0,0,0,0,0};
    const float* xr = x + (size_t)t * NC;
    for (int c = lane; c < NC; c += 64){
        float xv = xr[c];
        #pragma unroll
        for (int j = 0; j < 8; j++){
            ag[j] = fmaf(xv, Wg[c*8 + j], ag[j]);
            an[j] = fmaf(xv, Wn[c*8 + j], an[j]);
        }
    }
    #pragma unroll
    for (int j = 0; j < 8; j++){
        #pragma unroll
        for (int o = 32; o >= 1; o >>= 1){
            ag[j] += __shfl_xor(ag[j], o, 64);
            an[j] += __shfl_xor(an[j], o, 64);
        }
    }
    if (lane == 0){
        float lg[8];
        #pragma unroll
        for (int j = 0; j < 8; j++){
            float z = an[j];
            float sp = (z > 20.f) ? z : log1pf(expf(z));
            lg[j] = ag[j] + noise[(size_t)t*8 + j] * sp;
        }
        int i0 = 0; float v0 = lg[0];
        #pragma unroll
        for (int j = 1; j < 8; j++) if (lg[j] > v0){ v0 = lg[j]; i0 = j; }
        int i1 = -1; float v1 = -3.4e38f;
        #pragma unroll
        for (int j = 0; j < 8; j++) if (j != i0 && lg[j] > v1){ v1 = lg[j]; i1 = j; }
        float e1 = expf(v1 - v0);
        float w0 = 1.f / (1.f + e1);
        epair[2*t]   = i0;
        epair[2*t+1] = i1;
        wpair[2*t]   = w0;
        wpair[2*t+1] = e1 * w0;
    }
}

// ---------------------------------------------------------------------------
// Weight transpose + fp32->bf16:  Wt[e][n][k] = W[e][k][n]
// ---------------------------------------------------------------------------
__global__ void transpose_cvt(const float* __restrict__ W, unsigned short* __restrict__ Wt){
    __shared__ float t[32][33];
    size_t base = (size_t)blockIdx.z * NC * NC;
    int k0 = blockIdx.x * 32, n0 = blockIdx.y * 32;
    int tx = threadIdx.x, ty = threadIdx.y;
    #pragma unroll
    for (int i = 0; i < 4; i++)
        t[ty + i*8][tx] = W[base + (size_t)(k0 + ty + i*8)*NC + n0 + tx];
    __syncthreads();
    #pragma unroll
    for (int i = 0; i < 4; i++)
        Wt[base + (size_t)(n0 + ty + i*8)*NC + k0 + tx] = f2bf(t[tx][ty + i*8]);
}

// fp32 -> bf16, 4 elems/thread
__global__ void cvt_x(const float* __restrict__ x, unsigned short* __restrict__ xb){
    int idx = blockIdx.x * blockDim.x + threadIdx.x;   // < 1M
    float4 v = ((const float4*)x)[idx];
    ushort4 o;
    o.x = f2bf(v.x); o.y = f2bf(v.y); o.z = f2bf(v.z); o.w = f2bf(v.w);
    ((ushort4*)xb)[idx] = o;
}

// ---------------------------------------------------------------------------
// Grouping: group g = s*8+e.  Single block: counts, padded offsets, tile table,
// cursor init, perm init(-1).
// ---------------------------------------------------------------------------
__global__ void group_build(const int* __restrict__ epair, int* __restrict__ cursor,
                            int* __restrict__ tile_g, int* __restrict__ tile_pos,
                            int* __restrict__ ntiles, int* __restrict__ perm){
    __shared__ int cnt[16];
    int tid = threadIdx.x;
    if (tid < 16) cnt[tid] = 0;
    __syncthreads();
    for (int p = tid; p < 2*MBT; p += 256){
        int g = ((p & 1) << 3) | epair[p];
        atomicAdd(&cnt[g], 1);
    }
    for (int i = tid; i < PERM_CAP; i += 256) perm[i] = -1;
    __syncthreads();
    if (tid == 0){
        int off = 0, tt = 0;
        for (int g = 0; g < 16; g++){
            int c = cnt[g];
            cursor[g] = off;
            int nt = (c + 127) >> 7;
            for (int i = 0; i < nt; i++){ tile_g[tt] = g; tile_pos[tt] = off + i*128; tt++; }
            off += nt << 7;
        }
        ntiles[0] = tt;
    }
}

__global__ void fill_perm(const int* __restrict__ epair, int* __restrict__ cursor,
                          int* __restrict__ perm){
    int p = blockIdx.x * blockDim.x + threadIdx.x;
    if (p < 2*MBT){
        int g = ((p & 1) << 3) | epair[p];
        int pos = atomicAdd(&cursor[g], 1);
        perm[pos] = p;
    }
}

// ---------------------------------------------------------------------------
// GEMM: C[m][n] = sum_k A[m][k]*Bt[n][k]   (A row-major bf16, Bt = B^T bf16)
// Tile 128x128, BK=32, 4 waves, 16x16x32 MFMA, 4x4 frags/wave.
// MODE 0: plain (A=xb rows = mtile), store bf16.
// MODE 1: grouped q: A rows gathered via perm (x row p>>1), store bf16 at row p.
// MODE 2: grouped o: A rows = attn[s][t], epilogue: out[t] (=|+=) w[p]*val.
// ---------------------------------------------------------------------------
template<int MODE>
__global__ __launch_bounds__(256)
void gemm_k(const unsigned short* __restrict__ A,
            const unsigned short* __restrict__ Bt,
            void* __restrict__ Cout,
            const int* __restrict__ perm,
            const int* __restrict__ tile_g,
            const int* __restrict__ tile_pos,
            const int* __restrict__ ntiles,
            const float* __restrict__ wpair,
            int pass_s){
    int ntile = blockIdx.x;      // 8 col tiles
    int slot  = blockIdx.y;      // mtile (MODE0) or group tile slot
    int tpos = 0;
    const unsigned short* bt = Bt;
    if (MODE != 0){
        if (slot >= ntiles[0]) return;
        int g = tile_g[slot];
        if (MODE == 2 && (g >> 3) != pass_s) return;
        bt = Bt + (size_t)(g & 7) * NC * NC;
        tpos = tile_pos[slot];
    }
    __shared__ __align__(16) unsigned short As[128][40];
    __shared__ __align__(16) unsigned short Bs[128][40];
    int tid = threadIdx.x;
    int lane = tid & 63, wv = tid >> 6;
    int wr = wv >> 1, wc = wv & 1;
    int quad = lane >> 4, l15 = lane & 15;

    const unsigned short* ap[2];
    const unsigned short* bp[2];
    #pragma unroll
    for (int it = 0; it < 2; it++){
        int row = (tid >> 2) + it*64;
        int ko  = (tid & 3) * 8;
        if (MODE == 0){
            ap[it] = A + (size_t)(slot*128 + row) * NC + ko;
        } else {
            int p = perm[tpos + row];
            if (p >= 0){
                if (MODE == 1) ap[it] = A + (size_t)(p >> 1) * NC + ko;
                else           ap[it] = A + (size_t)(p & 1) * MBT * NC + (size_t)(p >> 1) * NC + ko;
            } else ap[it] = nullptr;
        }
        bp[it] = bt + (size_t)(ntile*128 + row) * NC + ko;
    }

    f32x4 acc[4][4];
    #pragma unroll
    for (int i = 0; i < 4; i++)
        #pragma unroll
        for (int j = 0; j < 4; j++) acc[i][j] = (f32x4){0.f,0.f,0.f,0.f};

    for (int kk = 0; kk < NC; kk += 32){
        #pragma unroll
        for (int it = 0; it < 2; it++){
            int row = (tid >> 2) + it*64;
            int ko  = (tid & 3) * 8;
            uint4 av = ap[it] ? *(const uint4*)(ap[it] + kk) : make_uint4(0,0,0,0);
            uint4 bv = *(const uint4*)(bp[it] + kk);
            *(uint4*)&As[row][ko] = av;
            *(uint4*)&Bs[row][ko] = bv;
        }
        __syncthreads();
        bf16x8 af[4], bfr[4];
        #pragma unroll
        for (int mi = 0; mi < 4; mi++) af[mi]  = *(const bf16x8*)&As[wr*64 + mi*16 + l15][quad*8];
        #pragma unroll
        for (int ni = 0; ni < 4; ni++) bfr[ni] = *(const bf16x8*)&Bs[wc*64 + ni*16 + l15][quad*8];
        #pragma unroll
        for (int mi = 0; mi < 4; mi++)
            #pragma unroll
            for (int ni = 0; ni < 4; ni++)
                acc[mi][ni] = __builtin_amdgcn_mfma_f32_16x16x32_bf16(af[mi], bfr[ni], acc[mi][ni], 0, 0, 0);
        __syncthreads();
    }

    int colbase = ntile*128 + wc*64 + l15;
    #pragma unroll
    for (int mi = 0; mi < 4; mi++){
        #pragma unroll
        for (int r = 0; r < 4; r++){
            int m = wr*64 + mi*16 + quad*4 + r;
            if (MODE == 0){
                unsigned short* co = (unsigned short*)Cout + (size_t)(slot*128 + m) * NC + colbase;
                #pragma unroll
                for (int ni = 0; ni < 4; ni++) co[ni*16] = f2bf(acc[mi][ni][r]);
            } else {
                int p = perm[tpos + m];
                if (p >= 0){
                    if (MODE == 1){
                        unsigned short* co = (unsigned short*)Cout + (size_t)p * NC + colbase;
                        #pragma unroll
                        for (int ni = 0; ni < 4; ni++) co[ni*16] = f2bf(acc[mi][ni][r]);
                    } else {
                        float w = wpair[p];
                        float* co = (float*)Cout + (size_t)(p >> 1) * NC + colbase;
                        if (pass_s == 0){
                            #pragma unroll
                            for (int ni = 0; ni < 4; ni++) co[ni*16] = w * acc[mi][ni][r];
                        } else {
                            #pragma unroll
                            for (int ni = 0; ni < 4; ni++) co[ni*16] += w * acc[mi][ni][r];
                        }
                    }
                }
            }
        }
    }
}

// ---------------------------------------------------------------------------
// Flash attention per selection s.  Block = (b,h,qgroup of 64 rows), 4 waves,
// wave = 16 q-rows.  Per 16-wide j-tile: S^T = K*Q^T (2 MFMAs, K-dim=64),
// online softmax (stats per q-col, cross-quad shuffles), P via per-wave LDS
// round-trip into B-operand layout, O^T += V^T*P^T (4 MFMAs, K padded 16->32
// with zeroed halves).
// ---------------------------------------------------------------------------
__global__ __launch_bounds__(256)
void attn_k(const unsigned short* __restrict__ qsel, const unsigned short* __restrict__ kb,
            const unsigned short* __restrict__ vb, unsigned short* __restrict__ attnb){
    int b = blockIdx.x >> 4, h = blockIdx.x & 15;
    int qg = blockIdx.y, s = blockIdx.z;
    int tid = threadIdx.x, lane = tid & 63, wv = tid >> 6;
    int quad = lane >> 4, l15 = lane & 15;
    int qt = qg*4 + wv;
    int i = qg*64 + wv*16 + l15;          // this lane's q sequence position

    __shared__ __align__(16) unsigned short ksh[16][72];
    __shared__ __align__(16) unsigned short vsh[64][40];   // vsh[d][j], cols 16..31 zeroed
    __shared__ float psh[4][16][17];

    const unsigned short* qrow = qsel + ((size_t)((b*TSEQ + i)*2 + s)) * NC + h*DHEAD;
    bf16x8 qf0 = *(const bf16x8*)(qrow + quad*8);
    bf16x8 qf1 = *(const bf16x8*)(qrow + 32 + quad*8);

    float m = -1e30f, l = 0.f;
    f32x4 oacc[4];
    #pragma unroll
    for (int c = 0; c < 4; c++) oacc[c] = (f32x4){0.f,0.f,0.f,0.f};

    int njt = qg*4 + 4;
    for (int jt = 0; jt < njt; jt++){
        #pragma unroll
        for (int it = 0; it < 2; it++){
            int slot = tid + it*256;
            int j = slot >> 5, d = (slot & 31) * 2;
            size_t src = (size_t)(b*TSEQ + jt*16 + j) * NC + h*DHEAD + d;
            *(unsigned int*)&ksh[j][d] = *(const unsigned int*)(kb + src);
            unsigned int vvv = *(const unsigned int*)(vb + src);
            vsh[d][j]     = (unsigned short)(vvv & 0xffff);
            vsh[d+1][j]   = (unsigned short)(vvv >> 16);
            vsh[d][j+16]  = 0;
            vsh[d+1][j+16]= 0;
        }
        __syncthreads();
        if (jt <= qt){
            bf16x8 kf0 = *(const bf16x8*)&ksh[l15][quad*8];
            bf16x8 kf1 = *(const bf16x8*)&ksh[l15][32 + quad*8];
            f32x4 sac = (f32x4){0.f,0.f,0.f,0.f};
            sac = __builtin_amdgcn_mfma_f32_16x16x32_bf16(kf0, qf0, sac, 0, 0, 0);
            sac = __builtin_amdgcn_mfma_f32_16x16x32_bf16(kf1, qf1, sac, 0, 0, 0);
            float sv[4];
            #pragma unroll
            for (int r = 0; r < 4; r++){
                sv[r] = sac[r] * 0.125f;
                if (jt == qt && (quad*4 + r) > l15) sv[r] = -1e30f;
            }
            float tm = fmaxf(fmaxf(sv[0], sv[1]), fmaxf(sv[2], sv[3]));
            tm = fmaxf(tm, __shfl_xor(tm, 16, 64));
            tm = fmaxf(tm, __shfl_xor(tm, 32, 64));
            float mn = fmaxf(m, tm);
            float alpha = __expf(m - mn);
            float pr[4]; float rs = 0.f;
            #pragma unroll
            for (int r = 0; r < 4; r++){ pr[r] = __expf(sv[r] - mn); rs += pr[r]; }
            rs += __shfl_xor(rs, 16, 64);
            rs += __shfl_xor(rs, 32, 64);
            l = l*alpha + rs; m = mn;
            #pragma unroll
            for (int c = 0; c < 4; c++) oacc[c] = oacc[c] * alpha;
            #pragma unroll
            for (int r = 0; r < 4; r++) psh[wv][quad*4 + r][l15] = pr[r];
            // same-wave LDS ops are in-order: no barrier needed
            bf16x8 pf;
            #pragma unroll
            for (int jj = 0; jj < 8; jj++){
                int jr = (quad*8 + jj) & 15;
                float pv = (quad < 2) ? psh[wv][jr][l15] : 0.f;
                pf[jj] = (short)f2bf(pv);
            }
            #pragma unroll
            for (int c = 0; c < 4; c++){
                bf16x8 vf = *(const bf16x8*)&vsh[c*16 + l15][quad*8];
                oacc[c] = __builtin_amdgcn_mfma_f32_16x16x32_bf16(vf, pf, oacc[c], 0, 0, 0);
            }
        }
        __syncthreads();
    }
    float inv = 1.f / l;
    unsigned short* orow = attnb + (size_t)s * MBT * NC + (size_t)(b*TSEQ + i) * NC + h*DHEAD;
    #pragma unroll
    for (int c = 0; c < 4; c++){
        ushort4 ov;
        ov.x = f2bf(oacc[c][0] * inv);
        ov.y = f2bf(oacc[c][1] * inv);
        ov.z = f2bf(oacc[c][2] * inv);
        ov.w = f2bf(oacc[c][3] * inv);
        *(ushort4*)(orow + c*16 + quad*4) = ov;
    }
}

// ---------------------------------------------------------------------------
extern "C" void kernel_launch(void* const* d_in, const int* in_sizes, int n_in,
                              void* d_out, int out_size, void* d_ws, size_t ws_size,
                              hipStream_t stream){
    (void)in_sizes; (void)n_in; (void)out_size; (void)ws_size;
    const float* x     = (const float*)d_in[0];
    const float* noise = (const float*)d_in[1];
    const float* Wk    = (const float*)d_in[2];
    const float* Wv    = (const float*)d_in[3];
    const float* Wq    = (const float*)d_in[4];
    const float* Wo    = (const float*)d_in[5];
    const float* Wg    = (const float*)d_in[6];
    const float* Wn    = (const float*)d_in[7];
    float* out = (float*)d_out;

    char* ws = (char*)d_ws;
    size_t off = 0;
    auto alloc = [&](size_t bytes) -> void* {
        void* p = ws + off;
        off += (bytes + 255) & ~(size_t)255;
        return p;
    };
    unsigned short* xb    = (unsigned short*)alloc((size_t)MBT*NC*2);
    unsigned short* kbuf  = (unsigned short*)alloc((size_t)MBT*NC*2);
    unsigned short* vbuf  = (unsigned short*)alloc((size_t)MBT*NC*2);
    unsigned short* qselb = (unsigned short*)alloc((size_t)MBT*2*NC*2);
    unsigned short* attnb = (unsigned short*)alloc((size_t)2*MBT*NC*2);
    unsigned short* Wkt   = (unsigned short*)alloc((size_t)NC*NC*2);
    unsigned short* Wvt   = (unsigned short*)alloc((size_t)NC*NC*2);
    unsigned short* Wqt   = (unsigned short*)alloc((size_t)NEXP*NC*NC*2);
    unsigned short* Wot   = (unsigned short*)alloc((size_t)NEXP*NC*NC*2);
    int*   epair   = (int*)alloc(2*MBT*4);
    float* wpair   = (float*)alloc(2*MBT*4);
    int*   perm    = (int*)alloc(PERM_CAP*4);
    int*   cursor  = (int*)alloc(16*4);
    int*   tile_g  = (int*)alloc(MAXTILES*4);
    int*   tile_pos= (int*)alloc(MAXTILES*4);
    int*   ntiles  = (int*)alloc(4);

    transpose_cvt<<<dim3(32,32,1), dim3(32,8), 0, stream>>>(Wk, Wkt);
    transpose_cvt<<<dim3(32,32,1), dim3(32,8), 0, stream>>>(Wv, Wvt);
    transpose_cvt<<<dim3(32,32,8), dim3(32,8), 0, stream>>>(Wq, Wqt);
    transpose_cvt<<<dim3(32,32,8), dim3(32,8), 0, stream>>>(Wo, Wot);
    cvt_x<<<4096, 256, 0, stream>>>(x, xb);
    gate_kernel<<<4096, 64, 0, stream>>>(x, noise, Wg, Wn, epair, wpair);
    group_build<<<1, 256, 0, stream>>>(epair, cursor, tile_g, tile_pos, ntiles, perm);
    fill_perm<<<32, 256, 0, stream>>>(epair, cursor, perm);

    gemm_k<0><<<dim3(8,32), 256, 0, stream>>>(xb, Wkt, kbuf, nullptr, nullptr, nullptr, nullptr, nullptr, 0);
    gemm_k<0><<<dim3(8,32), 256, 0, stream>>>(xb, Wvt, vbuf, nullptr, nullptr, nullptr, nullptr, nullptr, 0);
    gemm_k<1><<<dim3(8,MAXTILES), 256, 0, stream>>>(xb, Wqt, qselb, perm, tile_g, tile_pos, ntiles, nullptr, 0);

    attn_k<<<dim3(64,16,2), 256, 0, stream>>>(qselb, kbuf, vbuf, attnb);

    gemm_k<2><<<dim3(8,MAXTILES), 256, 0, stream>>>(attnb, Wot, out, perm, tile_g, tile_pos, ntiles, wpair, 0);
    gemm_k<2><<<dim3(8,MAXTILES), 256, 0, stream>>>(attnb, Wot, out, perm, tile_g, tile_pos, ntiles, wpair, 1);
}

// Round 2
// 464.953 us; speedup vs baseline: 1.1979x; 1.1979x over previous
//
#include <hip/hip_runtime.h>
#include <hip/hip_bf16.h>

// Problem constants
#define TSEQ   1024
#define NC     1024          // C
#define MBT    4096          // B*T
#define NEXP   8
#define NHEAD  16
#define DHEAD  64
#define PERM_CAP 10240       // 8192 pairs + 16 groups * 128 pad
#define MAXTILES 96

typedef __attribute__((ext_vector_type(8))) short bf16x8;
typedef __attribute__((ext_vector_type(4))) float f32x4;

static __device__ __forceinline__ unsigned short f2bf(float x){
    union { __hip_bfloat16 h; unsigned short u; } v;
    v.h = __float2bfloat16(x);
    return v.u;
}

// ---------------------------------------------------------------------------
// Gate: logits = x@Wg + noise*softplus(x@Wn); top2; softmax(2) -> epair/wpair
// ---------------------------------------------------------------------------
__global__ __launch_bounds__(64)
void gate_kernel(const float* __restrict__ x, const float* __restrict__ noise,
                 const float* __restrict__ Wg, const float* __restrict__ Wn,
                 int* __restrict__ epair, float* __restrict__ wpair){
    int t = blockIdx.x;
    int lane = threadIdx.x;
    float ag[8] = {0,0,0,0,0,0,0,0};
    float an[8] = {0,0,0,0,0,0,0,0};
    const float* xr = x + (size_t)t * NC;
    for (int c = lane; c < NC; c += 64){
        float xv = xr[c];
        #pragma unroll
        for (int j = 0; j < 8; j++){
            ag[j] = fmaf(xv, Wg[c*8 + j], ag[j]);
            an[j] = fmaf(xv, Wn[c*8 + j], an[j]);
        }
    }
    #pragma unroll
    for (int j = 0; j < 8; j++){
        #pragma unroll
        for (int o = 32; o >= 1; o >>= 1){
            ag[j] += __shfl_xor(ag[j], o, 64);
            an[j] += __shfl_xor(an[j], o, 64);
        }
    }
    if (lane == 0){
        float lg[8];
        #pragma unroll
        for (int j = 0; j < 8; j++){
            float z = an[j];
            float sp = (z > 20.f) ? z : log1pf(expf(z));
            lg[j] = ag[j] + noise[(size_t)t*8 + j] * sp;
        }
        int i0 = 0; float v0 = lg[0];
        #pragma unroll
        for (int j = 1; j < 8; j++) if (lg[j] > v0){ v0 = lg[j]; i0 = j; }
        int i1 = -1; float v1 = -3.4e38f;
        #pragma unroll
        for (int j = 0; j < 8; j++) if (j != i0 && lg[j] > v1){ v1 = lg[j]; i1 = j; }
        float e1 = expf(v1 - v0);
        float w0 = 1.f / (1.f + e1);
        epair[2*t]   = i0;
        epair[2*t+1] = i1;
        wpair[2*t]   = w0;
        wpair[2*t+1] = e1 * w0;
    }
}

// ---------------------------------------------------------------------------
// Weight transpose + fp32->bf16:  Wt[e][n][k] = W[e][k][n]
// ---------------------------------------------------------------------------
__global__ void transpose_cvt(const float* __restrict__ W, unsigned short* __restrict__ Wt){
    __shared__ float t[32][33];
    size_t base = (size_t)blockIdx.z * NC * NC;
    int k0 = blockIdx.x * 32, n0 = blockIdx.y * 32;
    int tx = threadIdx.x, ty = threadIdx.y;
    #pragma unroll
    for (int i = 0; i < 4; i++)
        t[ty + i*8][tx] = W[base + (size_t)(k0 + ty + i*8)*NC + n0 + tx];
    __syncthreads();
    #pragma unroll
    for (int i = 0; i < 4; i++)
        Wt[base + (size_t)(n0 + ty + i*8)*NC + k0 + tx] = f2bf(t[tx][ty + i*8]);
}

// fp32 -> bf16, 4 elems/thread
__global__ void cvt_x(const float* __restrict__ x, unsigned short* __restrict__ xb){
    int idx = blockIdx.x * blockDim.x + threadIdx.x;
    float4 v = ((const float4*)x)[idx];
    ushort4 o;
    o.x = f2bf(v.x); o.y = f2bf(v.y); o.z = f2bf(v.z); o.w = f2bf(v.w);
    ((ushort4*)xb)[idx] = o;
}

// ---------------------------------------------------------------------------
// vbuf [b*1024+t][h*64+d] -> vbufT [((b*16+h)*64+d)][t]   (bf16 transpose)
// ---------------------------------------------------------------------------
__global__ void transpose_v(const unsigned short* __restrict__ vbuf, unsigned short* __restrict__ vbT){
    __shared__ unsigned short sh[32][33];
    int b = blockIdx.z;
    int c0 = blockIdx.x * 32, t0 = blockIdx.y * 32;
    int tx = threadIdx.x, ty = threadIdx.y;
    #pragma unroll
    for (int i = 0; i < 4; i++)
        sh[ty + i*8][tx] = vbuf[((size_t)(b*TSEQ + t0 + ty + i*8))*NC + c0 + tx];
    __syncthreads();
    #pragma unroll
    for (int i = 0; i < 4; i++){
        int c = c0 + ty + i*8;
        vbT[((size_t)(b*NHEAD*DHEAD + c))*TSEQ + t0 + tx] = sh[tx][ty + i*8];
    }
}

// ---------------------------------------------------------------------------
// Grouping
// ---------------------------------------------------------------------------
__global__ void group_build(const int* __restrict__ epair, int* __restrict__ cursor,
                            int* __restrict__ tile_g, int* __restrict__ tile_pos,
                            int* __restrict__ ntiles, int* __restrict__ perm){
    __shared__ int cnt[16];
    int tid = threadIdx.x;
    if (tid < 16) cnt[tid] = 0;
    __syncthreads();
    for (int p = tid; p < 2*MBT; p += 256){
        int g = ((p & 1) << 3) | epair[p];
        atomicAdd(&cnt[g], 1);
    }
    for (int i = tid; i < PERM_CAP; i += 256) perm[i] = -1;
    __syncthreads();
    if (tid == 0){
        int off = 0, tt = 0;
        for (int g = 0; g < 16; g++){
            int c = cnt[g];
            cursor[g] = off;
            int nt = (c + 127) >> 7;
            for (int i = 0; i < nt; i++){ tile_g[tt] = g; tile_pos[tt] = off + i*128; tt++; }
            off += nt << 7;
        }
        ntiles[0] = tt;
    }
}

__global__ void fill_perm(const int* __restrict__ epair, int* __restrict__ cursor,
                          int* __restrict__ perm){
    int p = blockIdx.x * blockDim.x + threadIdx.x;
    if (p < 2*MBT){
        int g = ((p & 1) << 3) | epair[p];
        int pos = atomicAdd(&cursor[g], 1);
        perm[pos] = p;
    }
}

// ---------------------------------------------------------------------------
// GEMM 128x128x32, 4 waves, 16x16x32 MFMA (unchanged from round 1)
// ---------------------------------------------------------------------------
template<int MODE>
__global__ __launch_bounds__(256)
void gemm_k(const unsigned short* __restrict__ A,
            const unsigned short* __restrict__ Bt,
            void* __restrict__ Cout,
            const int* __restrict__ perm,
            const int* __restrict__ tile_g,
            const int* __restrict__ tile_pos,
            const int* __restrict__ ntiles,
            const float* __restrict__ wpair,
            int pass_s){
    int ntile = blockIdx.x;
    int slot  = blockIdx.y;
    int tpos = 0;
    const unsigned short* bt = Bt;
    if (MODE != 0){
        if (slot >= ntiles[0]) return;
        int g = tile_g[slot];
        if (MODE == 2 && (g >> 3) != pass_s) return;
        bt = Bt + (size_t)(g & 7) * NC * NC;
        tpos = tile_pos[slot];
    }
    __shared__ __align__(16) unsigned short As[128][40];
    __shared__ __align__(16) unsigned short Bs[128][40];
    int tid = threadIdx.x;
    int lane = tid & 63, wv = tid >> 6;
    int wr = wv >> 1, wc = wv & 1;
    int quad = lane >> 4, l15 = lane & 15;

    const unsigned short* ap[2];
    const unsigned short* bp[2];
    #pragma unroll
    for (int it = 0; it < 2; it++){
        int row = (tid >> 2) + it*64;
        int ko  = (tid & 3) * 8;
        if (MODE == 0){
            ap[it] = A + (size_t)(slot*128 + row) * NC + ko;
        } else {
            int p = perm[tpos + row];
            if (p >= 0){
                if (MODE == 1) ap[it] = A + (size_t)(p >> 1) * NC + ko;
                else           ap[it] = A + (size_t)(p & 1) * MBT * NC + (size_t)(p >> 1) * NC + ko;
            } else ap[it] = nullptr;
        }
        bp[it] = bt + (size_t)(ntile*128 + row) * NC + ko;
    }

    f32x4 acc[4][4];
    #pragma unroll
    for (int i = 0; i < 4; i++)
        #pragma unroll
        for (int j = 0; j < 4; j++) acc[i][j] = (f32x4){0.f,0.f,0.f,0.f};

    for (int kk = 0; kk < NC; kk += 32){
        #pragma unroll
        for (int it = 0; it < 2; it++){
            int row = (tid >> 2) + it*64;
            int ko  = (tid & 3) * 8;
            uint4 av = ap[it] ? *(const uint4*)(ap[it] + kk) : make_uint4(0,0,0,0);
            uint4 bv = *(const uint4*)(bp[it] + kk);
            *(uint4*)&As[row][ko] = av;
            *(uint4*)&Bs[row][ko] = bv;
        }
        __syncthreads();
        bf16x8 af[4], bfr[4];
        #pragma unroll
        for (int mi = 0; mi < 4; mi++) af[mi]  = *(const bf16x8*)&As[wr*64 + mi*16 + l15][quad*8];
        #pragma unroll
        for (int ni = 0; ni < 4; ni++) bfr[ni] = *(const bf16x8*)&Bs[wc*64 + ni*16 + l15][quad*8];
        #pragma unroll
        for (int mi = 0; mi < 4; mi++)
            #pragma unroll
            for (int ni = 0; ni < 4; ni++)
                acc[mi][ni] = __builtin_amdgcn_mfma_f32_16x16x32_bf16(af[mi], bfr[ni], acc[mi][ni], 0, 0, 0);
        __syncthreads();
    }

    int colbase = ntile*128 + wc*64 + l15;
    #pragma unroll
    for (int mi = 0; mi < 4; mi++){
        #pragma unroll
        for (int r = 0; r < 4; r++){
            int m = wr*64 + mi*16 + quad*4 + r;
            if (MODE == 0){
                unsigned short* co = (unsigned short*)Cout + (size_t)(slot*128 + m) * NC + colbase;
                #pragma unroll
                for (int ni = 0; ni < 4; ni++) co[ni*16] = f2bf(acc[mi][ni][r]);
            } else {
                int p = perm[tpos + m];
                if (p >= 0){
                    if (MODE == 1){
                        unsigned short* co = (unsigned short*)Cout + (size_t)p * NC + colbase;
                        #pragma unroll
                        for (int ni = 0; ni < 4; ni++) co[ni*16] = f2bf(acc[mi][ni][r]);
                    } else {
                        float w = wpair[p];
                        float* co = (float*)Cout + (size_t)(p >> 1) * NC + colbase;
                        if (pass_s == 0){
                            #pragma unroll
                            for (int ni = 0; ni < 4; ni++) co[ni*16] = w * acc[mi][ni][r];
                        } else {
                            #pragma unroll
                            for (int ni = 0; ni < 4; ni++) co[ni*16] += w * acc[mi][ni][r];
                        }
                    }
                }
            }
        }
    }
}

// ---------------------------------------------------------------------------
// Flash attention v2.  Block = (b*16+h, qblock of 128, s), 4 waves.
// Wave owns 32 q rows (2 i-subtiles of 16).  j-tile = 64.
// S^T = K*Q^T  (4 jsub x 2 isub x 2 khalf = 16 MFMAs), softmax stats on l15
// (2 shuffles per 64 j), P^T via per-wave LDS [j][i] (stride 35, ~2-way),
// O^T += V^T*P^T (16 MFMAs) with V^T staged from pre-transposed vbufT.
// Epilogue: O^T -> LDS -> coalesced 16B stores of attn[s][t][c].
// ---------------------------------------------------------------------------
__global__ __launch_bounds__(256)
void attn_k(const unsigned short* __restrict__ qsel, const unsigned short* __restrict__ kb,
            const unsigned short* __restrict__ vbT, unsigned short* __restrict__ attnb){
    int b = blockIdx.x >> 4, h = blockIdx.x & 15;
    int qb = blockIdx.y, s = blockIdx.z;
    int tid = threadIdx.x, lane = tid & 63, wv = tid >> 6;
    int quad = lane >> 4, l15 = lane & 15;
    int qbase = qb*128 + wv*32;              // wave's first q row

    __shared__ __align__(16) unsigned short ksh[64][72];
    __shared__ __align__(16) unsigned short vsh[64][72];
    __shared__ __align__(16) unsigned short pwork[4][2304];   // per-wave scratch

    int ig[2] = { qbase + l15, qbase + 16 + l15 };

    bf16x8 qf[2][2];
    #pragma unroll
    for (int isub = 0; isub < 2; isub++){
        const unsigned short* qrow = qsel + (((size_t)(b*TSEQ + qbase + isub*16 + l15))*2 + s)*NC + h*DHEAD;
        qf[isub][0] = *(const bf16x8*)(qrow + quad*8);
        qf[isub][1] = *(const bf16x8*)(qrow + 32 + quad*8);
    }

    float mrun[2] = {-1e30f, -1e30f}, lrun[2] = {0.f, 0.f};
    f32x4 oacc[4][2];
    #pragma unroll
    for (int d = 0; d < 4; d++)
        #pragma unroll
        for (int i = 0; i < 2; i++) oacc[d][i] = (f32x4){0.f,0.f,0.f,0.f};

    int njt = qb*2 + 2;
    for (int jt = 0; jt < njt; jt++){
        #pragma unroll
        for (int it = 0; it < 2; it++){
            int idx = it*256 + tid;
            int r = idx >> 3, c8 = (idx & 7) * 8;
            *(uint4*)&ksh[r][c8] = *(const uint4*)(kb + ((size_t)(b*TSEQ + jt*64 + r))*NC + h*DHEAD + c8);
            *(uint4*)&vsh[r][c8] = *(const uint4*)(vbT + ((size_t)(b*NHEAD*DHEAD + h*DHEAD + r))*TSEQ + jt*64 + c8);
        }
        __syncthreads();

        if (jt*64 <= qbase + 31){
            // --- QK^T (S^T orientation) ---
            f32x4 sac[4][2];
            #pragma unroll
            for (int jsub = 0; jsub < 4; jsub++){
                bf16x8 kf0 = *(const bf16x8*)&ksh[jsub*16 + l15][quad*8];
                bf16x8 kf1 = *(const bf16x8*)&ksh[jsub*16 + l15][32 + quad*8];
                #pragma unroll
                for (int isub = 0; isub < 2; isub++){
                    f32x4 z = (f32x4){0.f,0.f,0.f,0.f};
                    z = __builtin_amdgcn_mfma_f32_16x16x32_bf16(kf0, qf[isub][0], z, 0, 0, 0);
                    z = __builtin_amdgcn_mfma_f32_16x16x32_bf16(kf1, qf[isub][1], z, 0, 0, 0);
                    sac[jsub][isub] = z;
                }
            }
            bool need_mask = (jt*64 + 63 > qbase);
            float sv[2][16];
            #pragma unroll
            for (int jsub = 0; jsub < 4; jsub++){
                #pragma unroll
                for (int r = 0; r < 4; r++){
                    int j = jt*64 + jsub*16 + quad*4 + r;
                    #pragma unroll
                    for (int isub = 0; isub < 2; isub++){
                        float v = sac[jsub][isub][r] * 0.125f;
                        if (need_mask && j > ig[isub]) v = -1e30f;
                        sv[isub][jsub*4 + r] = v;
                    }
                }
            }
            #pragma unroll
            for (int isub = 0; isub < 2; isub++){
                float tm = sv[isub][0];
                #pragma unroll
                for (int k = 1; k < 16; k++) tm = fmaxf(tm, sv[isub][k]);
                tm = fmaxf(tm, __shfl_xor(tm, 16, 64));
                tm = fmaxf(tm, __shfl_xor(tm, 32, 64));
                float mn = fmaxf(mrun[isub], tm);
                float alpha = __expf(mrun[isub] - mn);
                float rs = 0.f;
                #pragma unroll
                for (int k = 0; k < 16; k++){
                    float p = __expf(sv[isub][k] - mn);
                    sv[isub][k] = p; rs += p;
                }
                rs += __shfl_xor(rs, 16, 64);
                rs += __shfl_xor(rs, 32, 64);
                lrun[isub] = lrun[isub]*alpha + rs; mrun[isub] = mn;
                #pragma unroll
                for (int d = 0; d < 4; d++) oacc[d][isub] = oacc[d][isub] * alpha;
                // store P^T[j][i] bf16, row stride 35 (odd -> ~2-way banks)
                #pragma unroll
                for (int jsub = 0; jsub < 4; jsub++)
                    #pragma unroll
                    for (int r = 0; r < 4; r++)
                        pwork[wv][(jsub*16 + quad*4 + r)*35 + isub*16 + l15] = f2bf(sv[isub][jsub*4 + r]);
            }
            // --- read P^T in B-operand layout (same wave, in-order LDS) ---
            bf16x8 pf[2][2];
            #pragma unroll
            for (int kh = 0; kh < 2; kh++)
                #pragma unroll
                for (int isub = 0; isub < 2; isub++)
                    #pragma unroll
                    for (int jj = 0; jj < 8; jj++)
                        pf[kh][isub][jj] = (short)pwork[wv][(kh*32 + quad*8 + jj)*35 + isub*16 + l15];
            // --- PV: O^T += V^T * P^T ---
            #pragma unroll
            for (int dsub = 0; dsub < 4; dsub++){
                bf16x8 vf0 = *(const bf16x8*)&vsh[dsub*16 + l15][quad*8];
                bf16x8 vf1 = *(const bf16x8*)&vsh[dsub*16 + l15][32 + quad*8];
                #pragma unroll
                for (int isub = 0; isub < 2; isub++){
                    oacc[dsub][isub] = __builtin_amdgcn_mfma_f32_16x16x32_bf16(vf0, pf[0][isub], oacc[dsub][isub], 0, 0, 0);
                    oacc[dsub][isub] = __builtin_amdgcn_mfma_f32_16x16x32_bf16(vf1, pf[1][isub], oacc[dsub][isub], 0, 0, 0);
                }
            }
        }
        __syncthreads();
    }

    // epilogue: normalize, transpose via per-wave LDS, coalesced stores
    float inv[2] = { 1.f / lrun[0], 1.f / lrun[1] };
    #pragma unroll
    for (int dsub = 0; dsub < 4; dsub++)
        #pragma unroll
        for (int isub = 0; isub < 2; isub++)
            #pragma unroll
            for (int r = 0; r < 4; r++)
                pwork[wv][(isub*16 + l15)*72 + dsub*16 + quad*4 + r] = f2bf(oacc[dsub][isub][r] * inv[isub]);
    #pragma unroll
    for (int rr = 0; rr < 4; rr++){
        int idx = rr*64 + lane;
        int il = idx >> 3, c8 = (idx & 7) * 8;
        int t = qb*128 + wv*32 + il;
        *(uint4*)(attnb + (size_t)s*MBT*NC + ((size_t)(b*TSEQ + t))*NC + h*DHEAD + c8) =
            *(const uint4*)&pwork[wv][il*72 + c8];
    }
}

// ---------------------------------------------------------------------------
extern "C" void kernel_launch(void* const* d_in, const int* in_sizes, int n_in,
                              void* d_out, int out_size, void* d_ws, size_t ws_size,
                              hipStream_t stream){
    (void)in_sizes; (void)n_in; (void)out_size; (void)ws_size;
    const float* x     = (const float*)d_in[0];
    const float* noise = (const float*)d_in[1];
    const float* Wk    = (const float*)d_in[2];
    const float* Wv    = (const float*)d_in[3];
    const float* Wq    = (const float*)d_in[4];
    const float* Wo    = (const float*)d_in[5];
    const float* Wg    = (const float*)d_in[6];
    const float* Wn    = (const float*)d_in[7];
    float* out = (float*)d_out;

    char* ws = (char*)d_ws;
    size_t off = 0;
    auto alloc = [&](size_t bytes) -> void* {
        void* p = ws + off;
        off += (bytes + 255) & ~(size_t)255;
        return p;
    };
    unsigned short* xb    = (unsigned short*)alloc((size_t)MBT*NC*2);
    unsigned short* kbuf  = (unsigned short*)alloc((size_t)MBT*NC*2);
    unsigned short* vbuf  = (unsigned short*)alloc((size_t)MBT*NC*2);
    unsigned short* vbufT = (unsigned short*)alloc((size_t)MBT*NC*2);
    unsigned short* qselb = (unsigned short*)alloc((size_t)MBT*2*NC*2);
    unsigned short* attnb = (unsigned short*)alloc((size_t)2*MBT*NC*2);
    unsigned short* Wkt   = (unsigned short*)alloc((size_t)NC*NC*2);
    unsigned short* Wvt   = (unsigned short*)alloc((size_t)NC*NC*2);
    unsigned short* Wqt   = (unsigned short*)alloc((size_t)NEXP*NC*NC*2);
    unsigned short* Wot   = (unsigned short*)alloc((size_t)NEXP*NC*NC*2);
    int*   epair   = (int*)alloc(2*MBT*4);
    float* wpair   = (float*)alloc(2*MBT*4);
    int*   perm    = (int*)alloc(PERM_CAP*4);
    int*   cursor  = (int*)alloc(16*4);
    int*   tile_g  = (int*)alloc(MAXTILES*4);
    int*   tile_pos= (int*)alloc(MAXTILES*4);
    int*   ntiles  = (int*)alloc(4);

    transpose_cvt<<<dim3(32,32,1), dim3(32,8), 0, stream>>>(Wk, Wkt);
    transpose_cvt<<<dim3(32,32,1), dim3(32,8), 0, stream>>>(Wv, Wvt);
    transpose_cvt<<<dim3(32,32,8), dim3(32,8), 0, stream>>>(Wq, Wqt);
    transpose_cvt<<<dim3(32,32,8), dim3(32,8), 0, stream>>>(Wo, Wot);
    cvt_x<<<4096, 256, 0, stream>>>(x, xb);
    gate_kernel<<<4096, 64, 0, stream>>>(x, noise, Wg, Wn, epair, wpair);
    group_build<<<1, 256, 0, stream>>>(epair, cursor, tile_g, tile_pos, ntiles, perm);
    fill_perm<<<32, 256, 0, stream>>>(epair, cursor, perm);

    gemm_k<0><<<dim3(8,32), 256, 0, stream>>>(xb, Wkt, kbuf, nullptr, nullptr, nullptr, nullptr, nullptr, 0);
    gemm_k<0><<<dim3(8,32), 256, 0, stream>>>(xb, Wvt, vbuf, nullptr, nullptr, nullptr, nullptr, nullptr, 0);
    transpose_v<<<dim3(32,32,4), dim3(32,8), 0, stream>>>(vbuf, vbufT);
    gemm_k<1><<<dim3(8,MAXTILES), 256, 0, stream>>>(xb, Wqt, qselb, perm, tile_g, tile_pos, ntiles, nullptr, 0);

    attn_k<<<dim3(64,8,2), 256, 0, stream>>>(qselb, kbuf, vbufT, attnb);

    gemm_k<2><<<dim3(8,MAXTILES), 256, 0, stream>>>(attnb, Wot, out, perm, tile_g, tile_pos, ntiles, wpair, 0);
    gemm_k<2><<<dim3(8,MAXTILES), 256, 0, stream>>>(attnb, Wot, out, perm, tile_g, tile_pos, ntiles, wpair, 1);
}

// Round 3
// 389.710 us; speedup vs baseline: 1.4292x; 1.1931x over previous
//
#include <hip/hip_runtime.h>
#include <hip/hip_bf16.h>

// Problem constants
#define TSEQ   1024
#define NC     1024          // C
#define MBT    4096          // B*T
#define NEXP   8
#define NHEAD  16
#define DHEAD  64
#define PERM_CAP 10240       // 8192 pairs + 16 groups * 128 pad
#define MAXTILES 96

typedef __attribute__((ext_vector_type(8))) short bf16x8;
typedef __attribute__((ext_vector_type(4))) float f32x4;

static __device__ __forceinline__ unsigned short f2bf(float x){
    union { __hip_bfloat16 h; unsigned short u; } v;
    v.h = __float2bfloat16(x);
    return v.u;
}

// ---------------------------------------------------------------------------
// Gate
// ---------------------------------------------------------------------------
__global__ __launch_bounds__(64)
void gate_kernel(const float* __restrict__ x, const float* __restrict__ noise,
                 const float* __restrict__ Wg, const float* __restrict__ Wn,
                 int* __restrict__ epair, float* __restrict__ wpair){
    int t = blockIdx.x;
    int lane = threadIdx.x;
    float ag[8] = {0,0,0,0,0,0,0,0};
    float an[8] = {0,0,0,0,0,0,0,0};
    const float* xr = x + (size_t)t * NC;
    for (int c = lane; c < NC; c += 64){
        float xv = xr[c];
        #pragma unroll
        for (int j = 0; j < 8; j++){
            ag[j] = fmaf(xv, Wg[c*8 + j], ag[j]);
            an[j] = fmaf(xv, Wn[c*8 + j], an[j]);
        }
    }
    #pragma unroll
    for (int j = 0; j < 8; j++){
        #pragma unroll
        for (int o = 32; o >= 1; o >>= 1){
            ag[j] += __shfl_xor(ag[j], o, 64);
            an[j] += __shfl_xor(an[j], o, 64);
        }
    }
    if (lane == 0){
        float lg[8];
        #pragma unroll
        for (int j = 0; j < 8; j++){
            float z = an[j];
            float sp = (z > 20.f) ? z : log1pf(expf(z));
            lg[j] = ag[j] + noise[(size_t)t*8 + j] * sp;
        }
        int i0 = 0; float v0 = lg[0];
        #pragma unroll
        for (int j = 1; j < 8; j++) if (lg[j] > v0){ v0 = lg[j]; i0 = j; }
        int i1 = -1; float v1 = -3.4e38f;
        #pragma unroll
        for (int j = 0; j < 8; j++) if (j != i0 && lg[j] > v1){ v1 = lg[j]; i1 = j; }
        float e1 = expf(v1 - v0);
        float w0 = 1.f / (1.f + e1);
        epair[2*t]   = i0;
        epair[2*t+1] = i1;
        wpair[2*t]   = w0;
        wpair[2*t+1] = e1 * w0;
    }
}

// ---------------------------------------------------------------------------
// Weight transpose + fp32->bf16:  Wt[e][n][k] = W[e][k][n]
// ---------------------------------------------------------------------------
__global__ void transpose_cvt(const float* __restrict__ W, unsigned short* __restrict__ Wt){
    __shared__ float t[32][33];
    size_t base = (size_t)blockIdx.z * NC * NC;
    int k0 = blockIdx.x * 32, n0 = blockIdx.y * 32;
    int tx = threadIdx.x, ty = threadIdx.y;
    #pragma unroll
    for (int i = 0; i < 4; i++)
        t[ty + i*8][tx] = W[base + (size_t)(k0 + ty + i*8)*NC + n0 + tx];
    __syncthreads();
    #pragma unroll
    for (int i = 0; i < 4; i++)
        Wt[base + (size_t)(n0 + ty + i*8)*NC + k0 + tx] = f2bf(t[tx][ty + i*8]);
}

// fp32 -> bf16, 4 elems/thread
__global__ void cvt_x(const float* __restrict__ x, unsigned short* __restrict__ xb){
    int idx = blockIdx.x * blockDim.x + threadIdx.x;
    float4 v = ((const float4*)x)[idx];
    ushort4 o;
    o.x = f2bf(v.x); o.y = f2bf(v.y); o.z = f2bf(v.z); o.w = f2bf(v.w);
    ((ushort4*)xb)[idx] = o;
}

// ---------------------------------------------------------------------------
// kvbuf [b*1024+t][2048] (V half at +1024) -> vbufT [(b*1024+c)][t]
// ---------------------------------------------------------------------------
__global__ void transpose_v(const unsigned short* __restrict__ kvb, unsigned short* __restrict__ vbT){
    __shared__ unsigned short sh[32][33];
    int b = blockIdx.z;
    int c0 = blockIdx.x * 32, t0 = blockIdx.y * 32;
    int tx = threadIdx.x, ty = threadIdx.y;
    #pragma unroll
    for (int i = 0; i < 4; i++)
        sh[ty + i*8][tx] = kvb[((size_t)(b*TSEQ + t0 + ty + i*8))*2048 + 1024 + c0 + tx];
    __syncthreads();
    #pragma unroll
    for (int i = 0; i < 4; i++){
        int c = c0 + ty + i*8;
        vbT[((size_t)(b*NC + c))*TSEQ + t0 + tx] = sh[tx][ty + i*8];
    }
}

// ---------------------------------------------------------------------------
// Grouping
// ---------------------------------------------------------------------------
__global__ void group_build(const int* __restrict__ epair, int* __restrict__ cursor,
                            int* __restrict__ tile_g, int* __restrict__ tile_pos,
                            int* __restrict__ ntiles, int* __restrict__ perm){
    __shared__ int cnt[16];
    int tid = threadIdx.x;
    if (tid < 16) cnt[tid] = 0;
    __syncthreads();
    for (int p = tid; p < 2*MBT; p += 256){
        int g = ((p & 1) << 3) | epair[p];
        atomicAdd(&cnt[g], 1);
    }
    for (int i = tid; i < PERM_CAP; i += 256) perm[i] = -1;
    __syncthreads();
    if (tid == 0){
        int off = 0, tt = 0;
        for (int g = 0; g < 16; g++){
            int c = cnt[g];
            cursor[g] = off;
            int nt = (c + 127) >> 7;
            for (int i = 0; i < nt; i++){ tile_g[tt] = g; tile_pos[tt] = off + i*128; tt++; }
            off += nt << 7;
        }
        ntiles[0] = tt;
    }
}

__global__ void fill_perm(const int* __restrict__ epair, int* __restrict__ cursor,
                          int* __restrict__ perm){
    int p = blockIdx.x * blockDim.x + threadIdx.x;
    if (p < 2*MBT){
        int g = ((p & 1) << 3) | epair[p];
        int pos = atomicAdd(&cursor[g], 1);
        perm[pos] = p;
    }
}

// ---------------------------------------------------------------------------
// GEMM 128x128, BK=64, 4 waves, 16x16x32 MFMA.
// MODE 0: plain A=xb, store bf16 stride nout.
// MODE 1: grouped q (perm gather), store bf16 * 0.125 at row p.
// MODE 2: grouped o, store fp32 w[p]*val into os[s = p&1][t][c], no read.
// ---------------------------------------------------------------------------
template<int MODE>
__global__ __launch_bounds__(256)
void gemm_k(const unsigned short* __restrict__ A,
            const unsigned short* __restrict__ Bt,
            void* __restrict__ Cout,
            const int* __restrict__ perm,
            const int* __restrict__ tile_g,
            const int* __restrict__ tile_pos,
            const int* __restrict__ ntiles,
            const float* __restrict__ wpair,
            int nout){
    int ntile = blockIdx.x;
    int slot  = blockIdx.y;
    int tpos = 0;
    const unsigned short* bt = Bt;
    if (MODE != 0){
        if (slot >= ntiles[0]) return;
        int g = tile_g[slot];
        bt = Bt + (size_t)(g & 7) * NC * NC;
        tpos = tile_pos[slot];
    }
    __shared__ __align__(16) unsigned short As[128][72];
    __shared__ __align__(16) unsigned short Bs[128][72];
    int tid = threadIdx.x;
    int lane = tid & 63, wv = tid >> 6;
    int wr = wv >> 1, wc = wv & 1;
    int quad = lane >> 4, l15 = lane & 15;

    int r0 = tid >> 3;               // 0..31
    int c8 = (tid & 7) * 8;          // 0..56
    const unsigned short* ap[4];
    const unsigned short* bp[4];
    #pragma unroll
    for (int i = 0; i < 4; i++){
        int row = r0 + i*32;
        if (MODE == 0){
            ap[i] = A + (size_t)(slot*128 + row) * NC + c8;
        } else {
            int p = perm[tpos + row];
            if (p >= 0){
                if (MODE == 1) ap[i] = A + (size_t)(p >> 1) * NC + c8;
                else           ap[i] = A + (size_t)(p & 1) * MBT * NC + (size_t)(p >> 1) * NC + c8;
            } else ap[i] = nullptr;
        }
        bp[i] = bt + (size_t)(ntile*128 + row) * NC + c8;
    }

    f32x4 acc[4][4];
    #pragma unroll
    for (int i = 0; i < 4; i++)
        #pragma unroll
        for (int j = 0; j < 4; j++) acc[i][j] = (f32x4){0.f,0.f,0.f,0.f};

    for (int kk = 0; kk < NC; kk += 64){
        #pragma unroll
        for (int i = 0; i < 4; i++){
            int row = r0 + i*32;
            uint4 av = ap[i] ? *(const uint4*)(ap[i] + kk) : make_uint4(0,0,0,0);
            uint4 bv = *(const uint4*)(bp[i] + kk);
            *(uint4*)&As[row][c8] = av;
            *(uint4*)&Bs[row][c8] = bv;
        }
        __syncthreads();
        #pragma unroll
        for (int kh = 0; kh < 2; kh++){
            bf16x8 af[4], bfr[4];
            #pragma unroll
            for (int mi = 0; mi < 4; mi++) af[mi]  = *(const bf16x8*)&As[wr*64 + mi*16 + l15][kh*32 + quad*8];
            #pragma unroll
            for (int ni = 0; ni < 4; ni++) bfr[ni] = *(const bf16x8*)&Bs[wc*64 + ni*16 + l15][kh*32 + quad*8];
            #pragma unroll
            for (int mi = 0; mi < 4; mi++)
                #pragma unroll
                for (int ni = 0; ni < 4; ni++)
                    acc[mi][ni] = __builtin_amdgcn_mfma_f32_16x16x32_bf16(af[mi], bfr[ni], acc[mi][ni], 0, 0, 0);
        }
        __syncthreads();
    }

    int colbase = ntile*128 + wc*64 + l15;
    #pragma unroll
    for (int mi = 0; mi < 4; mi++){
        #pragma unroll
        for (int r = 0; r < 4; r++){
            int m = wr*64 + mi*16 + quad*4 + r;
            if (MODE == 0){
                unsigned short* co = (unsigned short*)Cout + (size_t)(slot*128 + m) * nout + colbase;
                #pragma unroll
                for (int ni = 0; ni < 4; ni++) co[ni*16] = f2bf(acc[mi][ni][r]);
            } else {
                int p = perm[tpos + m];
                if (p >= 0){
                    if (MODE == 1){
                        unsigned short* co = (unsigned short*)Cout + (size_t)p * NC + colbase;
                        #pragma unroll
                        for (int ni = 0; ni < 4; ni++) co[ni*16] = f2bf(0.125f * acc[mi][ni][r]);
                    } else {
                        float w = wpair[p];
                        float* co = (float*)Cout + (size_t)(p & 1) * MBT * NC + (size_t)(p >> 1) * NC + colbase;
                        #pragma unroll
                        for (int ni = 0; ni < 4; ni++) co[ni*16] = w * acc[mi][ni][r];
                    }
                }
            }
        }
    }
}

// os0 + os1 -> out (fp32)
__global__ void combine(const float* __restrict__ os, float* __restrict__ out){
    size_t i = ((size_t)blockIdx.x * 256 + threadIdx.x) * 4;
    float4 a = *(const float4*)(os + i);
    float4 b = *(const float4*)(os + (size_t)MBT*NC + i);
    float4 r; r.x = a.x+b.x; r.y = a.y+b.y; r.z = a.z+b.z; r.w = a.w+b.w;
    *(float4*)(out + i) = r;
}

// ---------------------------------------------------------------------------
// Flash attention v3.  Block = (qpair, b*16+h, s).  Processes q-blocks
// qb = blockIdx.x and 7-blockIdx.x -> uniform 9 tile-units per block.
// Wave owns 32 q rows; j-tile = 64; q pre-scaled by 1/8 in gemm<1>.
// P round-trip: store P[i][j] rows (ushort4 x8), read B-frags (ds_read_b128 x4).
// ---------------------------------------------------------------------------
__global__ __launch_bounds__(256)
void attn_k(const unsigned short* __restrict__ qsel, const unsigned short* __restrict__ kvb,
            const unsigned short* __restrict__ vbT, unsigned short* __restrict__ attnb){
    int b = blockIdx.y >> 4, h = blockIdx.y & 15;
    int s = blockIdx.z;
    int tid = threadIdx.x, lane = tid & 63, wv = tid >> 6;
    int quad = lane >> 4, l15 = lane & 15;

    __shared__ __align__(16) unsigned short ksh[64][72];
    __shared__ __align__(16) unsigned short vsh[64][72];
    __shared__ __align__(16) unsigned short pwork[4][32][72];

    #pragma unroll
    for (int half = 0; half < 2; half++){
        int qb = half ? (7 - blockIdx.x) : blockIdx.x;
        int qbase = qb*128 + wv*32;
        int ig[2] = { qbase + l15, qbase + 16 + l15 };

        bf16x8 qf[2][2];
        #pragma unroll
        for (int isub = 0; isub < 2; isub++){
            const unsigned short* qrow = qsel + (((size_t)(b*TSEQ + qbase + isub*16 + l15))*2 + s)*NC + h*DHEAD;
            qf[isub][0] = *(const bf16x8*)(qrow + quad*8);
            qf[isub][1] = *(const bf16x8*)(qrow + 32 + quad*8);
        }

        float mrun[2] = {-1e30f, -1e30f}, lrun[2] = {0.f, 0.f};
        f32x4 oacc[4][2];
        #pragma unroll
        for (int d = 0; d < 4; d++)
            #pragma unroll
            for (int i = 0; i < 2; i++) oacc[d][i] = (f32x4){0.f,0.f,0.f,0.f};

        int njt = qb*2 + 2;
        for (int jt = 0; jt < njt; jt++){
            #pragma unroll
            for (int it = 0; it < 2; it++){
                int idx = it*256 + tid;
                int r = idx >> 3, cc = (idx & 7) * 8;
                *(uint4*)&ksh[r][cc] = *(const uint4*)(kvb + ((size_t)(b*TSEQ + jt*64 + r))*2048 + h*DHEAD + cc);
                *(uint4*)&vsh[r][cc] = *(const uint4*)(vbT + ((size_t)(b*NC + h*DHEAD + r))*TSEQ + jt*64 + cc);
            }
            __syncthreads();

            if (jt*64 <= qbase + 31){
                // --- QK^T (S^T orientation) ---
                f32x4 sac[4][2];
                #pragma unroll
                for (int jsub = 0; jsub < 4; jsub++){
                    bf16x8 kf0 = *(const bf16x8*)&ksh[jsub*16 + l15][quad*8];
                    bf16x8 kf1 = *(const bf16x8*)&ksh[jsub*16 + l15][32 + quad*8];
                    #pragma unroll
                    for (int isub = 0; isub < 2; isub++){
                        f32x4 z = (f32x4){0.f,0.f,0.f,0.f};
                        z = __builtin_amdgcn_mfma_f32_16x16x32_bf16(kf0, qf[isub][0], z, 0, 0, 0);
                        z = __builtin_amdgcn_mfma_f32_16x16x32_bf16(kf1, qf[isub][1], z, 0, 0, 0);
                        sac[jsub][isub] = z;
                    }
                }
                bool need_mask = (jt*64 + 63 > qbase);
                float sv[2][16];
                #pragma unroll
                for (int jsub = 0; jsub < 4; jsub++){
                    #pragma unroll
                    for (int r = 0; r < 4; r++){
                        int j = jt*64 + jsub*16 + quad*4 + r;
                        #pragma unroll
                        for (int isub = 0; isub < 2; isub++){
                            float v = sac[jsub][isub][r];
                            if (need_mask && j > ig[isub]) v = -1e30f;
                            sv[isub][jsub*4 + r] = v;
                        }
                    }
                }
                #pragma unroll
                for (int isub = 0; isub < 2; isub++){
                    float tm = sv[isub][0];
                    #pragma unroll
                    for (int k = 1; k < 16; k++) tm = fmaxf(tm, sv[isub][k]);
                    tm = fmaxf(tm, __shfl_xor(tm, 16, 64));
                    tm = fmaxf(tm, __shfl_xor(tm, 32, 64));
                    float mn = fmaxf(mrun[isub], tm);
                    float alpha = __expf(mrun[isub] - mn);
                    float rs = 0.f;
                    #pragma unroll
                    for (int k = 0; k < 16; k++){
                        float p = __expf(sv[isub][k] - mn);
                        sv[isub][k] = p; rs += p;
                    }
                    rs += __shfl_xor(rs, 16, 64);
                    rs += __shfl_xor(rs, 32, 64);
                    lrun[isub] = lrun[isub]*alpha + rs; mrun[isub] = mn;
                    #pragma unroll
                    for (int d = 0; d < 4; d++) oacc[d][isub] = oacc[d][isub] * alpha;
                    // store P[i][j] rows: 4 consecutive j per ushort4
                    #pragma unroll
                    for (int jsub = 0; jsub < 4; jsub++){
                        ushort4 pk;
                        pk.x = f2bf(sv[isub][jsub*4 + 0]);
                        pk.y = f2bf(sv[isub][jsub*4 + 1]);
                        pk.z = f2bf(sv[isub][jsub*4 + 2]);
                        pk.w = f2bf(sv[isub][jsub*4 + 3]);
                        *(ushort4*)&pwork[wv][isub*16 + l15][jsub*16 + quad*4] = pk;
                    }
                }
                // --- read P as B-operand (same wave, in-order LDS) ---
                bf16x8 pf[2][2];
                #pragma unroll
                for (int kh = 0; kh < 2; kh++)
                    #pragma unroll
                    for (int isub = 0; isub < 2; isub++)
                        pf[kh][isub] = *(const bf16x8*)&pwork[wv][isub*16 + l15][kh*32 + quad*8];
                // --- PV: O^T += V^T * P^T ---
                #pragma unroll
                for (int dsub = 0; dsub < 4; dsub++){
                    bf16x8 vf0 = *(const bf16x8*)&vsh[dsub*16 + l15][quad*8];
                    bf16x8 vf1 = *(const bf16x8*)&vsh[dsub*16 + l15][32 + quad*8];
                    #pragma unroll
                    for (int isub = 0; isub < 2; isub++){
                        oacc[dsub][isub] = __builtin_amdgcn_mfma_f32_16x16x32_bf16(vf0, pf[0][isub], oacc[dsub][isub], 0, 0, 0);
                        oacc[dsub][isub] = __builtin_amdgcn_mfma_f32_16x16x32_bf16(vf1, pf[1][isub], oacc[dsub][isub], 0, 0, 0);
                    }
                }
            }
            __syncthreads();
        }

        // epilogue: normalize, transpose via per-wave LDS, coalesced stores
        float inv[2] = { 1.f / lrun[0], 1.f / lrun[1] };
        #pragma unroll
        for (int dsub = 0; dsub < 4; dsub++)
            #pragma unroll
            for (int isub = 0; isub < 2; isub++){
                ushort4 ok;
                ok.x = f2bf(oacc[dsub][isub][0] * inv[isub]);
                ok.y = f2bf(oacc[dsub][isub][1] * inv[isub]);
                ok.z = f2bf(oacc[dsub][isub][2] * inv[isub]);
                ok.w = f2bf(oacc[dsub][isub][3] * inv[isub]);
                *(ushort4*)&pwork[wv][isub*16 + l15][dsub*16 + quad*4] = ok;
            }
        #pragma unroll
        for (int rr = 0; rr < 4; rr++){
            int idx = rr*64 + lane;
            int il = idx >> 3, cc = (idx & 7) * 8;
            int t = qb*128 + wv*32 + il;
            *(uint4*)(attnb + (size_t)s*MBT*NC + ((size_t)(b*TSEQ + t))*NC + h*DHEAD + cc) =
                *(const uint4*)&pwork[wv][il][cc];
        }
    }
}

// ---------------------------------------------------------------------------
extern "C" void kernel_launch(void* const* d_in, const int* in_sizes, int n_in,
                              void* d_out, int out_size, void* d_ws, size_t ws_size,
                              hipStream_t stream){
    (void)in_sizes; (void)n_in; (void)out_size; (void)ws_size;
    const float* x     = (const float*)d_in[0];
    const float* noise = (const float*)d_in[1];
    const float* Wk    = (const float*)d_in[2];
    const float* Wv    = (const float*)d_in[3];
    const float* Wq    = (const float*)d_in[4];
    const float* Wo    = (const float*)d_in[5];
    const float* Wg    = (const float*)d_in[6];
    const float* Wn    = (const float*)d_in[7];
    float* out = (float*)d_out;

    char* ws = (char*)d_ws;
    size_t off = 0;
    auto alloc = [&](size_t bytes) -> void* {
        void* p = ws + off;
        off += (bytes + 255) & ~(size_t)255;
        return p;
    };
    unsigned short* xb    = (unsigned short*)alloc((size_t)MBT*NC*2);
    unsigned short* vbufT = (unsigned short*)alloc((size_t)MBT*NC*2);
    unsigned short* kvbuf = (unsigned short*)alloc((size_t)MBT*2048*2);  // K|V, stride 2048
    unsigned short* qselb = (unsigned short*)alloc((size_t)MBT*2*NC*2);  // contiguous after kvbuf
    unsigned short* attnb = (unsigned short*)alloc((size_t)2*MBT*NC*2);
    unsigned short* Wkvt  = (unsigned short*)alloc((size_t)2*NC*NC*2);
    unsigned short* Wqt   = (unsigned short*)alloc((size_t)NEXP*NC*NC*2);
    unsigned short* Wot   = (unsigned short*)alloc((size_t)NEXP*NC*NC*2);
    int*   epair   = (int*)alloc(2*MBT*4);
    float* wpair   = (float*)alloc(2*MBT*4);
    int*   perm    = (int*)alloc(PERM_CAP*4);
    int*   cursor  = (int*)alloc(16*4);
    int*   tile_g  = (int*)alloc(MAXTILES*4);
    int*   tile_pos= (int*)alloc(MAXTILES*4);
    int*   ntiles  = (int*)alloc(4);

    // os[2][MBT][NC] fp32 aliases kvbuf+qselb (both dead after attn; sizes match)
    float* osbuf = (float*)kvbuf;

    transpose_cvt<<<dim3(32,32,1), dim3(32,8), 0, stream>>>(Wk, Wkvt);
    transpose_cvt<<<dim3(32,32,1), dim3(32,8), 0, stream>>>(Wv, Wkvt + (size_t)NC*NC);
    transpose_cvt<<<dim3(32,32,8), dim3(32,8), 0, stream>>>(Wq, Wqt);
    transpose_cvt<<<dim3(32,32,8), dim3(32,8), 0, stream>>>(Wo, Wot);
    cvt_x<<<4096, 256, 0, stream>>>(x, xb);
    gate_kernel<<<4096, 64, 0, stream>>>(x, noise, Wg, Wn, epair, wpair);
    group_build<<<1, 256, 0, stream>>>(epair, cursor, tile_g, tile_pos, ntiles, perm);
    fill_perm<<<32, 256, 0, stream>>>(epair, cursor, perm);

    // fused K|V projection: N=2048
    gemm_k<0><<<dim3(16,32), 256, 0, stream>>>(xb, Wkvt, kvbuf, nullptr, nullptr, nullptr, nullptr, nullptr, 2048);
    transpose_v<<<dim3(32,32,4), dim3(32,8), 0, stream>>>(kvbuf, vbufT);
    gemm_k<1><<<dim3(8,MAXTILES), 256, 0, stream>>>(xb, Wqt, qselb, perm, tile_g, tile_pos, ntiles, nullptr, NC);

    attn_k<<<dim3(4,64,2), 256, 0, stream>>>(qselb, kvbuf, vbufT, attnb);

    gemm_k<2><<<dim3(8,MAXTILES), 256, 0, stream>>>(attnb, Wot, osbuf, perm, tile_g, tile_pos, ntiles, wpair, NC);
    combine<<<4096, 256, 0, stream>>>(osbuf, out);
}

// Round 4
// 372.391 us; speedup vs baseline: 1.4956x; 1.0465x over previous
//
#include <hip/hip_runtime.h>
#include <hip/hip_bf16.h>

// Problem constants
#define TSEQ   1024
#define NC     1024          // C
#define MBT    4096          // B*T
#define NEXP   8
#define NHEAD  16
#define DHEAD  64
#define PERM_CAP 10240       // 8192 pairs + 16 groups * 128 pad
#define MAXTILES 96

typedef __attribute__((ext_vector_type(8))) short bf16x8;
typedef __attribute__((ext_vector_type(4))) float f32x4;

typedef __attribute__((address_space(3))) unsigned char* lds_ptr_t;
typedef const __attribute__((address_space(1))) unsigned char* glb_ptr_t;

// async global->LDS DMA, 16B per lane, dest = wave-uniform base + lane*16
static __device__ __forceinline__ void gload16(const void* g, void* l){
    __builtin_amdgcn_global_load_lds((glb_ptr_t)g, (lds_ptr_t)l, 16, 0, 0);
}

static __device__ __forceinline__ unsigned short f2bf(float x){
    union { __hip_bfloat16 h; unsigned short u; } v;
    v.h = __float2bfloat16(x);
    return v.u;
}

// ---------------------------------------------------------------------------
// Gate
// ---------------------------------------------------------------------------
__global__ __launch_bounds__(64)
void gate_kernel(const float* __restrict__ x, const float* __restrict__ noise,
                 const float* __restrict__ Wg, const float* __restrict__ Wn,
                 int* __restrict__ epair, float* __restrict__ wpair){
    int t = blockIdx.x;
    int lane = threadIdx.x;
    float ag[8] = {0,0,0,0,0,0,0,0};
    float an[8] = {0,0,0,0,0,0,0,0};
    const float* xr = x + (size_t)t * NC;
    for (int c = lane; c < NC; c += 64){
        float xv = xr[c];
        #pragma unroll
        for (int j = 0; j < 8; j++){
            ag[j] = fmaf(xv, Wg[c*8 + j], ag[j]);
            an[j] = fmaf(xv, Wn[c*8 + j], an[j]);
        }
    }
    #pragma unroll
    for (int j = 0; j < 8; j++){
        #pragma unroll
        for (int o = 32; o >= 1; o >>= 1){
            ag[j] += __shfl_xor(ag[j], o, 64);
            an[j] += __shfl_xor(an[j], o, 64);
        }
    }
    if (lane == 0){
        float lg[8];
        #pragma unroll
        for (int j = 0; j < 8; j++){
            float z = an[j];
            float sp = (z > 20.f) ? z : log1pf(expf(z));
            lg[j] = ag[j] + noise[(size_t)t*8 + j] * sp;
        }
        int i0 = 0; float v0 = lg[0];
        #pragma unroll
        for (int j = 1; j < 8; j++) if (lg[j] > v0){ v0 = lg[j]; i0 = j; }
        int i1 = -1; float v1 = -3.4e38f;
        #pragma unroll
        for (int j = 0; j < 8; j++) if (j != i0 && lg[j] > v1){ v1 = lg[j]; i1 = j; }
        float e1 = expf(v1 - v0);
        float w0 = 1.f / (1.f + e1);
        epair[2*t]   = i0;
        epair[2*t+1] = i1;
        wpair[2*t]   = w0;
        wpair[2*t+1] = e1 * w0;
    }
}

// ---------------------------------------------------------------------------
// Weight transpose + fp32->bf16:  Wt[e][n][k] = W[e][k][n]
// ---------------------------------------------------------------------------
__global__ void transpose_cvt(const float* __restrict__ W, unsigned short* __restrict__ Wt){
    __shared__ float t[32][33];
    size_t base = (size_t)blockIdx.z * NC * NC;
    int k0 = blockIdx.x * 32, n0 = blockIdx.y * 32;
    int tx = threadIdx.x, ty = threadIdx.y;
    #pragma unroll
    for (int i = 0; i < 4; i++)
        t[ty + i*8][tx] = W[base + (size_t)(k0 + ty + i*8)*NC + n0 + tx];
    __syncthreads();
    #pragma unroll
    for (int i = 0; i < 4; i++)
        Wt[base + (size_t)(n0 + ty + i*8)*NC + k0 + tx] = f2bf(t[tx][ty + i*8]);
}

// fp32 -> bf16, 4 elems/thread
__global__ void cvt_x(const float* __restrict__ x, unsigned short* __restrict__ xb){
    int idx = blockIdx.x * blockDim.x + threadIdx.x;
    float4 v = ((const float4*)x)[idx];
    ushort4 o;
    o.x = f2bf(v.x); o.y = f2bf(v.y); o.z = f2bf(v.z); o.w = f2bf(v.w);
    ((ushort4*)xb)[idx] = o;
}

// ---------------------------------------------------------------------------
// kvbuf [b*1024+t][2048] (V half at +1024) -> vbufT [(b*1024+c)][t]
// ---------------------------------------------------------------------------
__global__ void transpose_v(const unsigned short* __restrict__ kvb, unsigned short* __restrict__ vbT){
    __shared__ unsigned short sh[32][33];
    int b = blockIdx.z;
    int c0 = blockIdx.x * 32, t0 = blockIdx.y * 32;
    int tx = threadIdx.x, ty = threadIdx.y;
    #pragma unroll
    for (int i = 0; i < 4; i++)
        sh[ty + i*8][tx] = kvb[((size_t)(b*TSEQ + t0 + ty + i*8))*2048 + 1024 + c0 + tx];
    __syncthreads();
    #pragma unroll
    for (int i = 0; i < 4; i++){
        int c = c0 + ty + i*8;
        vbT[((size_t)(b*NC + c))*TSEQ + t0 + tx] = sh[tx][ty + i*8];
    }
}

// ---------------------------------------------------------------------------
// Grouping
// ---------------------------------------------------------------------------
__global__ void group_build(const int* __restrict__ epair, int* __restrict__ cursor,
                            int* __restrict__ tile_g, int* __restrict__ tile_pos,
                            int* __restrict__ ntiles, int* __restrict__ perm){
    __shared__ int cnt[16];
    int tid = threadIdx.x;
    if (tid < 16) cnt[tid] = 0;
    __syncthreads();
    for (int p = tid; p < 2*MBT; p += 256){
        int g = ((p & 1) << 3) | epair[p];
        atomicAdd(&cnt[g], 1);
    }
    for (int i = tid; i < PERM_CAP; i += 256) perm[i] = -1;
    __syncthreads();
    if (tid == 0){
        int off = 0, tt = 0;
        for (int g = 0; g < 16; g++){
            int c = cnt[g];
            cursor[g] = off;
            int nt = (c + 127) >> 7;
            for (int i = 0; i < nt; i++){ tile_g[tt] = g; tile_pos[tt] = off + i*128; tt++; }
            off += nt << 7;
        }
        ntiles[0] = tt;
    }
}

__global__ void fill_perm(const int* __restrict__ epair, int* __restrict__ cursor,
                          int* __restrict__ perm){
    int p = blockIdx.x * blockDim.x + threadIdx.x;
    if (p < 2*MBT){
        int g = ((p & 1) << 3) | epair[p];
        int pos = atomicAdd(&cursor[g], 1);
        perm[pos] = p;
    }
}

// ---------------------------------------------------------------------------
// GEMM 128x128, BK=64, 4 waves, 16x16x32 MFMA, global_load_lds staging with
// XOR-swizzled chunk layout (unpadded LDS rows of 64 ushorts).
// LDS slot c of row r holds global chunk c ^ (r&7); reader fetches q^(r&7).
// MODE 0: plain A=xb, store bf16 stride nout.
// MODE 1: grouped q (perm gather), store bf16 * 0.125 at row p.
// MODE 2: grouped o, store fp32 w[p]*val into os[s = p&1][t][c], no read.
// ---------------------------------------------------------------------------
template<int MODE>
__global__ __launch_bounds__(256)
void gemm_k(const unsigned short* __restrict__ A,
            const unsigned short* __restrict__ Bt,
            void* __restrict__ Cout,
            const int* __restrict__ perm,
            const int* __restrict__ tile_g,
            const int* __restrict__ tile_pos,
            const int* __restrict__ ntiles,
            const float* __restrict__ wpair,
            int nout){
    int ntile = blockIdx.x;
    int slot  = blockIdx.y;
    int tpos = 0;
    const unsigned short* bt = Bt;
    if (MODE != 0){
        if (slot >= ntiles[0]) return;
        int g = tile_g[slot];
        bt = Bt + (size_t)(g & 7) * NC * NC;
        tpos = tile_pos[slot];
    }
    __shared__ __align__(16) unsigned short As[128*64];
    __shared__ __align__(16) unsigned short Bs[128*64];
    int tid = threadIdx.x;
    int lane = tid & 63, wv = tid >> 6;
    int wr = wv >> 1, wc = wv & 1;
    int quad = lane >> 4, l15 = lane & 15;

    int laneR = lane >> 3;                   // row within 8-row issue group
    int swz = ((lane & 7) ^ (laneR & 7)) * 8; // fetched global chunk (ushorts)

    const unsigned short* ag[4];
    const unsigned short* bg[4];
    #pragma unroll
    for (int it = 0; it < 4; it++){
        int row = wv*32 + it*8 + laneR;
        if (MODE == 0){
            ag[it] = A + (size_t)(slot*128 + row) * NC + swz;
        } else {
            int p = perm[tpos + row];
            if (p < 0) p = 0;                // harmless: C row discarded at store
            if (MODE == 1) ag[it] = A + (size_t)(p >> 1) * NC + swz;
            else           ag[it] = A + (size_t)(p & 1) * MBT * NC + (size_t)(p >> 1) * NC + swz;
        }
        bg[it] = bt + (size_t)(ntile*128 + row) * NC + swz;
    }

    f32x4 acc[4][4];
    #pragma unroll
    for (int i = 0; i < 4; i++)
        #pragma unroll
        for (int j = 0; j < 4; j++) acc[i][j] = (f32x4){0.f,0.f,0.f,0.f};

    for (int kk = 0; kk < NC; kk += 64){
        #pragma unroll
        for (int it = 0; it < 4; it++){
            gload16(ag[it] + kk, &As[(wv*32 + it*8)*64]);
            gload16(bg[it] + kk, &Bs[(wv*32 + it*8)*64]);
        }
        __syncthreads();
        #pragma unroll
        for (int kh = 0; kh < 2; kh++){
            bf16x8 af[4], bfr[4];
            #pragma unroll
            for (int mi = 0; mi < 4; mi++)
                af[mi]  = *(const bf16x8*)&As[(wr*64 + mi*16 + l15)*64 + (((kh*4 + quad) ^ (l15 & 7))*8)];
            #pragma unroll
            for (int ni = 0; ni < 4; ni++)
                bfr[ni] = *(const bf16x8*)&Bs[(wc*64 + ni*16 + l15)*64 + (((kh*4 + quad) ^ (l15 & 7))*8)];
            #pragma unroll
            for (int mi = 0; mi < 4; mi++)
                #pragma unroll
                for (int ni = 0; ni < 4; ni++)
                    acc[mi][ni] = __builtin_amdgcn_mfma_f32_16x16x32_bf16(af[mi], bfr[ni], acc[mi][ni], 0, 0, 0);
        }
        __syncthreads();
    }

    int colbase = ntile*128 + wc*64 + l15;
    #pragma unroll
    for (int mi = 0; mi < 4; mi++){
        #pragma unroll
        for (int r = 0; r < 4; r++){
            int m = wr*64 + mi*16 + quad*4 + r;
            if (MODE == 0){
                unsigned short* co = (unsigned short*)Cout + (size_t)(slot*128 + m) * nout + colbase;
                #pragma unroll
                for (int ni = 0; ni < 4; ni++) co[ni*16] = f2bf(acc[mi][ni][r]);
            } else {
                int p = perm[tpos + m];
                if (p >= 0){
                    if (MODE == 1){
                        unsigned short* co = (unsigned short*)Cout + (size_t)p * NC + colbase;
                        #pragma unroll
                        for (int ni = 0; ni < 4; ni++) co[ni*16] = f2bf(0.125f * acc[mi][ni][r]);
                    } else {
                        float w = wpair[p];
                        float* co = (float*)Cout + (size_t)(p & 1) * MBT * NC + (size_t)(p >> 1) * NC + colbase;
                        #pragma unroll
                        for (int ni = 0; ni < 4; ni++) co[ni*16] = w * acc[mi][ni][r];
                    }
                }
            }
        }
    }
}

// os0 + os1 -> out (fp32)
__global__ void combine(const float* __restrict__ os, float* __restrict__ out){
    size_t i = ((size_t)blockIdx.x * 256 + threadIdx.x) * 4;
    float4 a = *(const float4*)(os + i);
    float4 b = *(const float4*)(os + (size_t)MBT*NC + i);
    float4 r; r.x = a.x+b.x; r.y = a.y+b.y; r.z = a.z+b.z; r.w = a.w+b.w;
    *(float4*)(out + i) = r;
}

// ---------------------------------------------------------------------------
// Flash attention v4: global_load_lds staging for K / V^T with the same XOR
// swizzle (unpadded 64-ushort rows).  Block = (qpair, b*16+h, s); qb pairing
// for causal balance.  Wave owns 32 q rows; j-tile = 64; q pre-scaled 1/8.
// ---------------------------------------------------------------------------
__global__ __launch_bounds__(256)
void attn_k(const unsigned short* __restrict__ qsel, const unsigned short* __restrict__ kvb,
            const unsigned short* __restrict__ vbT, unsigned short* __restrict__ attnb){
    int b = blockIdx.y >> 4, h = blockIdx.y & 15;
    int s = blockIdx.z;
    int tid = threadIdx.x, lane = tid & 63, wv = tid >> 6;
    int quad = lane >> 4, l15 = lane & 15;
    int laneR = lane >> 3;
    int swz = ((lane & 7) ^ (laneR & 7)) * 8;

    __shared__ __align__(16) unsigned short ksh[64*64];
    __shared__ __align__(16) unsigned short vsh[64*64];
    __shared__ __align__(16) unsigned short pwork[4][32][72];

    #pragma unroll
    for (int half = 0; half < 2; half++){
        int qb = half ? (7 - blockIdx.x) : blockIdx.x;
        int qbase = qb*128 + wv*32;
        int ig[2] = { qbase + l15, qbase + 16 + l15 };

        bf16x8 qf[2][2];
        #pragma unroll
        for (int isub = 0; isub < 2; isub++){
            const unsigned short* qrow = qsel + (((size_t)(b*TSEQ + qbase + isub*16 + l15))*2 + s)*NC + h*DHEAD;
            qf[isub][0] = *(const bf16x8*)(qrow + quad*8);
            qf[isub][1] = *(const bf16x8*)(qrow + 32 + quad*8);
        }

        float mrun[2] = {-1e30f, -1e30f}, lrun[2] = {0.f, 0.f};
        f32x4 oacc[4][2];
        #pragma unroll
        for (int d = 0; d < 4; d++)
            #pragma unroll
            for (int i = 0; i < 2; i++) oacc[d][i] = (f32x4){0.f,0.f,0.f,0.f};

        int njt = qb*2 + 2;
        for (int jt = 0; jt < njt; jt++){
            #pragma unroll
            for (int it = 0; it < 2; it++){
                int r = wv*16 + it*8 + laneR;
                gload16(kvb + ((size_t)(b*TSEQ + jt*64 + r))*2048 + h*DHEAD + swz,
                        &ksh[(wv*16 + it*8)*64]);
                gload16(vbT + ((size_t)(b*NC + h*DHEAD + r))*TSEQ + jt*64 + swz,
                        &vsh[(wv*16 + it*8)*64]);
            }
            __syncthreads();

            if (jt*64 <= qbase + 31){
                // --- QK^T (S^T orientation) ---
                f32x4 sac[4][2];
                #pragma unroll
                for (int jsub = 0; jsub < 4; jsub++){
                    bf16x8 kf0 = *(const bf16x8*)&ksh[(jsub*16 + l15)*64 + ((quad     ^ (l15 & 7))*8)];
                    bf16x8 kf1 = *(const bf16x8*)&ksh[(jsub*16 + l15)*64 + (((4+quad) ^ (l15 & 7))*8)];
                    #pragma unroll
                    for (int isub = 0; isub < 2; isub++){
                        f32x4 z = (f32x4){0.f,0.f,0.f,0.f};
                        z = __builtin_amdgcn_mfma_f32_16x16x32_bf16(kf0, qf[isub][0], z, 0, 0, 0);
                        z = __builtin_amdgcn_mfma_f32_16x16x32_bf16(kf1, qf[isub][1], z, 0, 0, 0);
                        sac[jsub][isub] = z;
                    }
                }
                bool need_mask = (jt*64 + 63 > qbase);
                float sv[2][16];
                #pragma unroll
                for (int jsub = 0; jsub < 4; jsub++){
                    #pragma unroll
                    for (int r = 0; r < 4; r++){
                        int j = jt*64 + jsub*16 + quad*4 + r;
                        #pragma unroll
                        for (int isub = 0; isub < 2; isub++){
                            float v = sac[jsub][isub][r];
                            if (need_mask && j > ig[isub]) v = -1e30f;
                            sv[isub][jsub*4 + r] = v;
                        }
                    }
                }
                #pragma unroll
                for (int isub = 0; isub < 2; isub++){
                    float tm = sv[isub][0];
                    #pragma unroll
                    for (int k = 1; k < 16; k++) tm = fmaxf(tm, sv[isub][k]);
                    tm = fmaxf(tm, __shfl_xor(tm, 16, 64));
                    tm = fmaxf(tm, __shfl_xor(tm, 32, 64));
                    float mn = fmaxf(mrun[isub], tm);
                    float alpha = __expf(mrun[isub] - mn);
                    float rs = 0.f;
                    #pragma unroll
                    for (int k = 0; k < 16; k++){
                        float p = __expf(sv[isub][k] - mn);
                        sv[isub][k] = p; rs += p;
                    }
                    rs += __shfl_xor(rs, 16, 64);
                    rs += __shfl_xor(rs, 32, 64);
                    lrun[isub] = lrun[isub]*alpha + rs; mrun[isub] = mn;
                    #pragma unroll
                    for (int d = 0; d < 4; d++) oacc[d][isub] = oacc[d][isub] * alpha;
                    #pragma unroll
                    for (int jsub = 0; jsub < 4; jsub++){
                        ushort4 pk;
                        pk.x = f2bf(sv[isub][jsub*4 + 0]);
                        pk.y = f2bf(sv[isub][jsub*4 + 1]);
                        pk.z = f2bf(sv[isub][jsub*4 + 2]);
                        pk.w = f2bf(sv[isub][jsub*4 + 3]);
                        *(ushort4*)&pwork[wv][isub*16 + l15][jsub*16 + quad*4] = pk;
                    }
                }
                // --- read P as B-operand (same wave, in-order LDS) ---
                bf16x8 pf[2][2];
                #pragma unroll
                for (int kh = 0; kh < 2; kh++)
                    #pragma unroll
                    for (int isub = 0; isub < 2; isub++)
                        pf[kh][isub] = *(const bf16x8*)&pwork[wv][isub*16 + l15][kh*32 + quad*8];
                // --- PV: O^T += V^T * P^T ---
                #pragma unroll
                for (int dsub = 0; dsub < 4; dsub++){
                    bf16x8 vf0 = *(const bf16x8*)&vsh[(dsub*16 + l15)*64 + ((quad     ^ (l15 & 7))*8)];
                    bf16x8 vf1 = *(const bf16x8*)&vsh[(dsub*16 + l15)*64 + (((4+quad) ^ (l15 & 7))*8)];
                    #pragma unroll
                    for (int isub = 0; isub < 2; isub++){
                        oacc[dsub][isub] = __builtin_amdgcn_mfma_f32_16x16x32_bf16(vf0, pf[0][isub], oacc[dsub][isub], 0, 0, 0);
                        oacc[dsub][isub] = __builtin_amdgcn_mfma_f32_16x16x32_bf16(vf1, pf[1][isub], oacc[dsub][isub], 0, 0, 0);
                    }
                }
            }
            __syncthreads();
        }

        // epilogue: normalize, transpose via per-wave LDS, coalesced stores
        float inv[2] = { 1.f / lrun[0], 1.f / lrun[1] };
        #pragma unroll
        for (int dsub = 0; dsub < 4; dsub++)
            #pragma unroll
            for (int isub = 0; isub < 2; isub++){
                ushort4 ok;
                ok.x = f2bf(oacc[dsub][isub][0] * inv[isub]);
                ok.y = f2bf(oacc[dsub][isub][1] * inv[isub]);
                ok.z = f2bf(oacc[dsub][isub][2] * inv[isub]);
                ok.w = f2bf(oacc[dsub][isub][3] * inv[isub]);
                *(ushort4*)&pwork[wv][isub*16 + l15][dsub*16 + quad*4] = ok;
            }
        #pragma unroll
        for (int rr = 0; rr < 4; rr++){
            int idx = rr*64 + lane;
            int il = idx >> 3, cc = (idx & 7) * 8;
            int t = qb*128 + wv*32 + il;
            *(uint4*)(attnb + (size_t)s*MBT*NC + ((size_t)(b*TSEQ + t))*NC + h*DHEAD + cc) =
                *(const uint4*)&pwork[wv][il][cc];
        }
    }
}

// ---------------------------------------------------------------------------
extern "C" void kernel_launch(void* const* d_in, const int* in_sizes, int n_in,
                              void* d_out, int out_size, void* d_ws, size_t ws_size,
                              hipStream_t stream){
    (void)in_sizes; (void)n_in; (void)out_size; (void)ws_size;
    const float* x     = (const float*)d_in[0];
    const float* noise = (const float*)d_in[1];
    const float* Wk    = (const float*)d_in[2];
    const float* Wv    = (const float*)d_in[3];
    const float* Wq    = (const float*)d_in[4];
    const float* Wo    = (const float*)d_in[5];
    const float* Wg    = (const float*)d_in[6];
    const float* Wn    = (const float*)d_in[7];
    float* out = (float*)d_out;

    char* ws = (char*)d_ws;
    size_t off = 0;
    auto alloc = [&](size_t bytes) -> void* {
        void* p = ws + off;
        off += (bytes + 255) & ~(size_t)255;
        return p;
    };
    unsigned short* xb    = (unsigned short*)alloc((size_t)MBT*NC*2);
    unsigned short* vbufT = (unsigned short*)alloc((size_t)MBT*NC*2);
    unsigned short* kvbuf = (unsigned short*)alloc((size_t)MBT*2048*2);  // K|V, stride 2048
    unsigned short* qselb = (unsigned short*)alloc((size_t)MBT*2*NC*2);  // contiguous after kvbuf
    unsigned short* attnb = (unsigned short*)alloc((size_t)2*MBT*NC*2);
    unsigned short* Wkvt  = (unsigned short*)alloc((size_t)2*NC*NC*2);
    unsigned short* Wqt   = (unsigned short*)alloc((size_t)NEXP*NC*NC*2);
    unsigned short* Wot   = (unsigned short*)alloc((size_t)NEXP*NC*NC*2);
    int*   epair   = (int*)alloc(2*MBT*4);
    float* wpair   = (float*)alloc(2*MBT*4);
    int*   perm    = (int*)alloc(PERM_CAP*4);
    int*   cursor  = (int*)alloc(16*4);
    int*   tile_g  = (int*)alloc(MAXTILES*4);
    int*   tile_pos= (int*)alloc(MAXTILES*4);
    int*   ntiles  = (int*)alloc(4);

    // os[2][MBT][NC] fp32 aliases kvbuf+qselb (both dead after attn; sizes match)
    float* osbuf = (float*)kvbuf;

    transpose_cvt<<<dim3(32,32,1), dim3(32,8), 0, stream>>>(Wk, Wkvt);
    transpose_cvt<<<dim3(32,32,1), dim3(32,8), 0, stream>>>(Wv, Wkvt + (size_t)NC*NC);
    transpose_cvt<<<dim3(32,32,8), dim3(32,8), 0, stream>>>(Wq, Wqt);
    transpose_cvt<<<dim3(32,32,8), dim3(32,8), 0, stream>>>(Wo, Wot);
    cvt_x<<<4096, 256, 0, stream>>>(x, xb);
    gate_kernel<<<4096, 64, 0, stream>>>(x, noise, Wg, Wn, epair, wpair);
    group_build<<<1, 256, 0, stream>>>(epair, cursor, tile_g, tile_pos, ntiles, perm);
    fill_perm<<<32, 256, 0, stream>>>(epair, cursor, perm);

    // fused K|V projection: N=2048
    gemm_k<0><<<dim3(16,32), 256, 0, stream>>>(xb, Wkvt, kvbuf, nullptr, nullptr, nullptr, nullptr, nullptr, 2048);
    transpose_v<<<dim3(32,32,4), dim3(32,8), 0, stream>>>(kvbuf, vbufT);
    gemm_k<1><<<dim3(8,MAXTILES), 256, 0, stream>>>(xb, Wqt, qselb, perm, tile_g, tile_pos, ntiles, nullptr, NC);

    attn_k<<<dim3(4,64,2), 256, 0, stream>>>(qselb, kvbuf, vbufT, attnb);

    gemm_k<2><<<dim3(8,MAXTILES), 256, 0, stream>>>(attnb, Wot, osbuf, perm, tile_g, tile_pos, ntiles, wpair, NC);
    combine<<<4096, 256, 0, stream>>>(osbuf, out);
}

// Round 5
// 364.222 us; speedup vs baseline: 1.5292x; 1.0224x over previous
//
#include <hip/hip_runtime.h>
#include <hip/hip_bf16.h>

// Problem constants
#define TSEQ   1024
#define NC     1024          // C
#define MBT    4096          // B*T
#define NEXP   8
#define NHEAD  16
#define DHEAD  64
#define PERM_CAP 10240       // 8192 pairs + 16 groups * 128 pad
#define MAXTILES 96

typedef __attribute__((ext_vector_type(8))) short bf16x8;
typedef __attribute__((ext_vector_type(4))) float f32x4;

typedef __attribute__((address_space(3))) unsigned char* lds_ptr_t;
typedef const __attribute__((address_space(1))) unsigned char* glb_ptr_t;

// async global->LDS DMA, 16B per lane, dest = wave-uniform base + lane*16
static __device__ __forceinline__ void gload16(const void* g, void* l){
    __builtin_amdgcn_global_load_lds((glb_ptr_t)g, (lds_ptr_t)l, 16, 0, 0);
}

// RNE fp32->bf16 (values are finite/normal here; no NaN path needed)
static __device__ __forceinline__ unsigned short f2bf(float x){
    unsigned int u = __float_as_uint(x);
    u += 0x7fff + ((u >> 16) & 1);
    return (unsigned short)(u >> 16);
}
static __device__ __forceinline__ unsigned int pk2bf(float a, float b){
    unsigned int ua = __float_as_uint(a), ub = __float_as_uint(b);
    ua += 0x7fff + ((ua >> 16) & 1);
    ub += 0x7fff + ((ub >> 16) & 1);
    return (ua >> 16) | (ub & 0xffff0000u);
}

// ---------------------------------------------------------------------------
// Gate: logits, top2, softmax(2).  Also emits xb = bf16(x) (replaces cvt_x).
// ---------------------------------------------------------------------------
__global__ __launch_bounds__(64)
void gate_kernel(const float* __restrict__ x, const float* __restrict__ noise,
                 const float* __restrict__ Wg, const float* __restrict__ Wn,
                 int* __restrict__ epair, float* __restrict__ wpair,
                 unsigned short* __restrict__ xb){
    int t = blockIdx.x;
    int lane = threadIdx.x;
    float ag[8] = {0,0,0,0,0,0,0,0};
    float an[8] = {0,0,0,0,0,0,0,0};
    const float* xr = x + (size_t)t * NC;
    unsigned short* xbr = xb + (size_t)t * NC;
    for (int c = lane; c < NC; c += 64){
        float xv = xr[c];
        xbr[c] = f2bf(xv);
        #pragma unroll
        for (int j = 0; j < 8; j++){
            ag[j] = fmaf(xv, Wg[c*8 + j], ag[j]);
            an[j] = fmaf(xv, Wn[c*8 + j], an[j]);
        }
    }
    #pragma unroll
    for (int j = 0; j < 8; j++){
        #pragma unroll
        for (int o = 32; o >= 1; o >>= 1){
            ag[j] += __shfl_xor(ag[j], o, 64);
            an[j] += __shfl_xor(an[j], o, 64);
        }
    }
    if (lane == 0){
        float lg[8];
        #pragma unroll
        for (int j = 0; j < 8; j++){
            float z = an[j];
            float sp = (z > 20.f) ? z : log1pf(expf(z));
            lg[j] = ag[j] + noise[(size_t)t*8 + j] * sp;
        }
        int i0 = 0; float v0 = lg[0];
        #pragma unroll
        for (int j = 1; j < 8; j++) if (lg[j] > v0){ v0 = lg[j]; i0 = j; }
        int i1 = -1; float v1 = -3.4e38f;
        #pragma unroll
        for (int j = 0; j < 8; j++) if (j != i0 && lg[j] > v1){ v1 = lg[j]; i1 = j; }
        float e1 = expf(v1 - v0);
        float w0 = 1.f / (1.f + e1);
        epair[2*t]   = i0;
        epair[2*t+1] = i1;
        wpair[2*t]   = w0;
        wpair[2*t+1] = e1 * w0;
    }
}

// ---------------------------------------------------------------------------
// All 18 weight transposes (Wk, Wv, 8xWq, 8xWo) in ONE launch.  z selects.
// ---------------------------------------------------------------------------
__global__ void prep_w(const float* __restrict__ Wk, const float* __restrict__ Wv,
                       const float* __restrict__ Wq, const float* __restrict__ Wo,
                       unsigned short* __restrict__ Wkvt, unsigned short* __restrict__ Wqt,
                       unsigned short* __restrict__ Wot){
    __shared__ float t[32][33];
    int z = blockIdx.z;
    const float* src; unsigned short* dst;
    if (z == 0){ src = Wk; dst = Wkvt; }
    else if (z == 1){ src = Wv; dst = Wkvt + (size_t)NC*NC; }
    else if (z < 10){ src = Wq + (size_t)(z-2)*NC*NC; dst = Wqt + (size_t)(z-2)*NC*NC; }
    else { src = Wo + (size_t)(z-10)*NC*NC; dst = Wot + (size_t)(z-10)*NC*NC; }
    int k0 = blockIdx.x * 32, n0 = blockIdx.y * 32;
    int tx = threadIdx.x, ty = threadIdx.y;
    #pragma unroll
    for (int i = 0; i < 4; i++)
        t[ty + i*8][tx] = src[(size_t)(k0 + ty + i*8)*NC + n0 + tx];
    __syncthreads();
    #pragma unroll
    for (int i = 0; i < 4; i++)
        dst[(size_t)(n0 + ty + i*8)*NC + k0 + tx] = f2bf(t[tx][ty + i*8]);
}

// ---------------------------------------------------------------------------
// kvbuf [b*1024+t][2048] (V half at +1024) -> vbufT [(b*1024+c)][t]
// ---------------------------------------------------------------------------
__global__ void transpose_v(const unsigned short* __restrict__ kvb, unsigned short* __restrict__ vbT){
    __shared__ unsigned short sh[32][33];
    int b = blockIdx.z;
    int c0 = blockIdx.x * 32, t0 = blockIdx.y * 32;
    int tx = threadIdx.x, ty = threadIdx.y;
    #pragma unroll
    for (int i = 0; i < 4; i++)
        sh[ty + i*8][tx] = kvb[((size_t)(b*TSEQ + t0 + ty + i*8))*2048 + 1024 + c0 + tx];
    __syncthreads();
    #pragma unroll
    for (int i = 0; i < 4; i++){
        int c = c0 + ty + i*8;
        vbT[((size_t)(b*NC + c))*TSEQ + t0 + tx] = sh[tx][ty + i*8];
    }
}

// ---------------------------------------------------------------------------
// Grouping
// ---------------------------------------------------------------------------
__global__ void group_build(const int* __restrict__ epair, int* __restrict__ cursor,
                            int* __restrict__ tile_g, int* __restrict__ tile_pos,
                            int* __restrict__ ntiles, int* __restrict__ perm){
    __shared__ int cnt[16];
    int tid = threadIdx.x;
    if (tid < 16) cnt[tid] = 0;
    __syncthreads();
    for (int p = tid; p < 2*MBT; p += 256){
        int g = ((p & 1) << 3) | epair[p];
        atomicAdd(&cnt[g], 1);
    }
    for (int i = tid; i < PERM_CAP; i += 256) perm[i] = -1;
    __syncthreads();
    if (tid == 0){
        int off = 0, tt = 0;
        for (int g = 0; g < 16; g++){
            int c = cnt[g];
            cursor[g] = off;
            int nt = (c + 127) >> 7;
            for (int i = 0; i < nt; i++){ tile_g[tt] = g; tile_pos[tt] = off + i*128; tt++; }
            off += nt << 7;
        }
        ntiles[0] = tt;
    }
}

// wave-aggregated scatter: one atomic per (wave, group) instead of per thread
__global__ __launch_bounds__(256)
void fill_perm(const int* __restrict__ epair, int* __restrict__ cursor,
               int* __restrict__ perm){
    int p = blockIdx.x * 256 + threadIdx.x;      // 32 blocks x 256 = 8192
    int lane = threadIdx.x & 63;
    int g = ((p & 1) << 3) | epair[p];
    unsigned long long ltmask = (lane == 63) ? 0x7fffffffffffffffull
                                             : (((unsigned long long)1 << lane) - 1);
    #pragma unroll 1
    for (int grp = 0; grp < 16; grp++){
        unsigned long long m = __ballot(g == grp);
        if (m == 0ull) continue;
        if (g == grp){
            int leader = __ffsll(m) - 1;
            int base = 0;
            if (lane == leader) base = atomicAdd(&cursor[grp], __popcll(m));
            base = __shfl(base, leader, 64);
            perm[base + __popcll(m & ltmask)] = p;
        }
    }
}

// ---------------------------------------------------------------------------
// Fused KV + Q GEMM, one launch (independent work items -> full-machine fill).
// Blocks [0,512): KV (plain A=xb, N=2048).  Blocks [512,1280): grouped Q.
// 128x128 tile, BK=64, global_load_lds + XOR swizzle, 16x16x32 MFMA.
// ---------------------------------------------------------------------------
__global__ __launch_bounds__(256)
void gemm_fused(const unsigned short* __restrict__ xb,
                const unsigned short* __restrict__ Wkvt,
                const unsigned short* __restrict__ Wqt,
                unsigned short* __restrict__ kvbuf,
                unsigned short* __restrict__ qselb,
                const int* __restrict__ perm,
                const int* __restrict__ tile_g,
                const int* __restrict__ tile_pos,
                const int* __restrict__ ntiles){
    int flat = blockIdx.x;
    bool isQ = (flat >= 512);
    int ntile, slot, tpos = 0;
    const unsigned short* bt;
    if (!isQ){
        ntile = flat & 15; slot = flat >> 4;
        bt = Wkvt;
    } else {
        int f2 = flat - 512;
        ntile = f2 & 7; slot = f2 >> 3;
        if (slot >= ntiles[0]) return;
        int g = tile_g[slot];
        bt = Wqt + (size_t)(g & 7) * NC * NC;
        tpos = tile_pos[slot];
    }

    __shared__ __align__(16) unsigned short As[128*64];
    __shared__ __align__(16) unsigned short Bs[128*64];
    int tid = threadIdx.x;
    int lane = tid & 63, wv = tid >> 6;
    int wr = wv >> 1, wc = wv & 1;
    int quad = lane >> 4, l15 = lane & 15;

    int laneR = lane >> 3;
    int swz = ((lane & 7) ^ (laneR & 7)) * 8;

    const unsigned short* ag[4];
    const unsigned short* bg[4];
    #pragma unroll
    for (int it = 0; it < 4; it++){
        int row = wv*32 + it*8 + laneR;
        if (!isQ){
            ag[it] = xb + (size_t)(slot*128 + row) * NC + swz;
        } else {
            int p = perm[tpos + row];
            if (p < 0) p = 0;                // harmless: C row discarded at store
            ag[it] = xb + (size_t)(p >> 1) * NC + swz;
        }
        bg[it] = bt + (size_t)(ntile*128 + row) * NC + swz;
    }

    f32x4 acc[4][4];
    #pragma unroll
    for (int i = 0; i < 4; i++)
        #pragma unroll
        for (int j = 0; j < 4; j++) acc[i][j] = (f32x4){0.f,0.f,0.f,0.f};

    for (int kk = 0; kk < NC; kk += 64){
        #pragma unroll
        for (int it = 0; it < 4; it++){
            gload16(ag[it] + kk, &As[(wv*32 + it*8)*64]);
            gload16(bg[it] + kk, &Bs[(wv*32 + it*8)*64]);
        }
        __syncthreads();
        #pragma unroll
        for (int kh = 0; kh < 2; kh++){
            bf16x8 af[4], bfr[4];
            #pragma unroll
            for (int mi = 0; mi < 4; mi++)
                af[mi]  = *(const bf16x8*)&As[(wr*64 + mi*16 + l15)*64 + (((kh*4 + quad) ^ (l15 & 7))*8)];
            #pragma unroll
            for (int ni = 0; ni < 4; ni++)
                bfr[ni] = *(const bf16x8*)&Bs[(wc*64 + ni*16 + l15)*64 + (((kh*4 + quad) ^ (l15 & 7))*8)];
            #pragma unroll
            for (int mi = 0; mi < 4; mi++)
                #pragma unroll
                for (int ni = 0; ni < 4; ni++)
                    acc[mi][ni] = __builtin_amdgcn_mfma_f32_16x16x32_bf16(af[mi], bfr[ni], acc[mi][ni], 0, 0, 0);
        }
        __syncthreads();
    }

    int colbase = ntile*128 + wc*64 + l15;
    #pragma unroll
    for (int mi = 0; mi < 4; mi++){
        #pragma unroll
        for (int r = 0; r < 4; r++){
            int m = wr*64 + mi*16 + quad*4 + r;
            if (!isQ){
                unsigned short* co = kvbuf + (size_t)(slot*128 + m) * 2048 + colbase;
                #pragma unroll
                for (int ni = 0; ni < 4; ni++) co[ni*16] = f2bf(acc[mi][ni][r]);
            } else {
                int p = perm[tpos + m];
                if (p >= 0){
                    unsigned short* co = qselb + (size_t)p * NC + colbase;
                    #pragma unroll
                    for (int ni = 0; ni < 4; ni++) co[ni*16] = f2bf(0.125f * acc[mi][ni][r]);
                }
            }
        }
    }
}

// ---------------------------------------------------------------------------
// O-projection GEMM (grouped, writes fp32 w[p]*val into os[p&1][t][c])
// ---------------------------------------------------------------------------
__global__ __launch_bounds__(256)
void gemm_o(const unsigned short* __restrict__ A,
            const unsigned short* __restrict__ Bt,
            float* __restrict__ Cout,
            const int* __restrict__ perm,
            const int* __restrict__ tile_g,
            const int* __restrict__ tile_pos,
            const int* __restrict__ ntiles,
            const float* __restrict__ wpair){
    int ntile = blockIdx.x;
    int slot  = blockIdx.y;
    if (slot >= ntiles[0]) return;
    int g = tile_g[slot];
    const unsigned short* bt = Bt + (size_t)(g & 7) * NC * NC;
    int tpos = tile_pos[slot];

    __shared__ __align__(16) unsigned short As[128*64];
    __shared__ __align__(16) unsigned short Bs[128*64];
    int tid = threadIdx.x;
    int lane = tid & 63, wv = tid >> 6;
    int wr = wv >> 1, wc = wv & 1;
    int quad = lane >> 4, l15 = lane & 15;

    int laneR = lane >> 3;
    int swz = ((lane & 7) ^ (laneR & 7)) * 8;

    const unsigned short* ag[4];
    const unsigned short* bg[4];
    #pragma unroll
    for (int it = 0; it < 4; it++){
        int row = wv*32 + it*8 + laneR;
        int p = perm[tpos + row];
        if (p < 0) p = 0;
        ag[it] = A + (size_t)(p & 1) * MBT * NC + (size_t)(p >> 1) * NC + swz;
        bg[it] = bt + (size_t)(ntile*128 + row) * NC + swz;
    }

    f32x4 acc[4][4];
    #pragma unroll
    for (int i = 0; i < 4; i++)
        #pragma unroll
        for (int j = 0; j < 4; j++) acc[i][j] = (f32x4){0.f,0.f,0.f,0.f};

    for (int kk = 0; kk < NC; kk += 64){
        #pragma unroll
        for (int it = 0; it < 4; it++){
            gload16(ag[it] + kk, &As[(wv*32 + it*8)*64]);
            gload16(bg[it] + kk, &Bs[(wv*32 + it*8)*64]);
        }
        __syncthreads();
        #pragma unroll
        for (int kh = 0; kh < 2; kh++){
            bf16x8 af[4], bfr[4];
            #pragma unroll
            for (int mi = 0; mi < 4; mi++)
                af[mi]  = *(const bf16x8*)&As[(wr*64 + mi*16 + l15)*64 + (((kh*4 + quad) ^ (l15 & 7))*8)];
            #pragma unroll
            for (int ni = 0; ni < 4; ni++)
                bfr[ni] = *(const bf16x8*)&Bs[(wc*64 + ni*16 + l15)*64 + (((kh*4 + quad) ^ (l15 & 7))*8)];
            #pragma unroll
            for (int mi = 0; mi < 4; mi++)
                #pragma unroll
                for (int ni = 0; ni < 4; ni++)
                    acc[mi][ni] = __builtin_amdgcn_mfma_f32_16x16x32_bf16(af[mi], bfr[ni], acc[mi][ni], 0, 0, 0);
        }
        __syncthreads();
    }

    int colbase = ntile*128 + wc*64 + l15;
    #pragma unroll
    for (int mi = 0; mi < 4; mi++){
        #pragma unroll
        for (int r = 0; r < 4; r++){
            int m = wr*64 + mi*16 + quad*4 + r;
            int p = perm[tpos + m];
            if (p >= 0){
                float w = wpair[p];
                float* co = Cout + (size_t)(p & 1) * MBT * NC + (size_t)(p >> 1) * NC + colbase;
                #pragma unroll
                for (int ni = 0; ni < 4; ni++) co[ni*16] = w * acc[mi][ni][r];
            }
        }
    }
}

// os0 + os1 -> out (fp32)
__global__ void combine(const float* __restrict__ os, float* __restrict__ out){
    size_t i = ((size_t)blockIdx.x * 256 + threadIdx.x) * 4;
    float4 a = *(const float4*)(os + i);
    float4 b = *(const float4*)(os + (size_t)MBT*NC + i);
    float4 r; r.x = a.x+b.x; r.y = a.y+b.y; r.z = a.z+b.z; r.w = a.w+b.w;
    *(float4*)(out + i) = r;
}

// ---------------------------------------------------------------------------
// Flash attention v5: fixed-max softmax (scores bounded; exp can't overflow),
// wave-uniform mask branch, packed RNE bf16 conversion.  Staging via
// global_load_lds + XOR swizzle.  Block = (qpair, b*16+h, s), qb pairing.
// ---------------------------------------------------------------------------
__global__ __launch_bounds__(256)
void attn_k(const unsigned short* __restrict__ qsel, const unsigned short* __restrict__ kvb,
            const unsigned short* __restrict__ vbT, unsigned short* __restrict__ attnb){
    int b = blockIdx.y >> 4, h = blockIdx.y & 15;
    int s = blockIdx.z;
    int tid = threadIdx.x, lane = tid & 63, wv = tid >> 6;
    int quad = lane >> 4, l15 = lane & 15;
    int laneR = lane >> 3;
    int swz = ((lane & 7) ^ (laneR & 7)) * 8;

    __shared__ __align__(16) unsigned short ksh[64*64];
    __shared__ __align__(16) unsigned short vsh[64*64];
    __shared__ __align__(16) unsigned short pwork[4][32][72];

    #pragma unroll
    for (int half = 0; half < 2; half++){
        int qb = half ? (7 - blockIdx.x) : blockIdx.x;
        int qbase = qb*128 + wv*32;
        int ig[2] = { qbase + l15, qbase + 16 + l15 };

        bf16x8 qf[2][2];
        #pragma unroll
        for (int isub = 0; isub < 2; isub++){
            const unsigned short* qrow = qsel + (((size_t)(b*TSEQ + qbase + isub*16 + l15))*2 + s)*NC + h*DHEAD;
            qf[isub][0] = *(const bf16x8*)(qrow + quad*8);
            qf[isub][1] = *(const bf16x8*)(qrow + 32 + quad*8);
        }

        float lrun[2] = {0.f, 0.f};
        f32x4 oacc[4][2];
        #pragma unroll
        for (int d = 0; d < 4; d++)
            #pragma unroll
            for (int i = 0; i < 2; i++) oacc[d][i] = (f32x4){0.f,0.f,0.f,0.f};

        int njt = qb*2 + 2;
        for (int jt = 0; jt < njt; jt++){
            #pragma unroll
            for (int it = 0; it < 2; it++){
                int r = wv*16 + it*8 + laneR;
                gload16(kvb + ((size_t)(b*TSEQ + jt*64 + r))*2048 + h*DHEAD + swz,
                        &ksh[(wv*16 + it*8)*64]);
                gload16(vbT + ((size_t)(b*NC + h*DHEAD + r))*TSEQ + jt*64 + swz,
                        &vsh[(wv*16 + it*8)*64]);
            }
            __syncthreads();

            if (jt*64 <= qbase + 31){
                // --- QK^T (S^T orientation); q pre-scaled by 1/8 ---
                f32x4 sac[4][2];
                #pragma unroll
                for (int jsub = 0; jsub < 4; jsub++){
                    bf16x8 kf0 = *(const bf16x8*)&ksh[(jsub*16 + l15)*64 + ((quad     ^ (l15 & 7))*8)];
                    bf16x8 kf1 = *(const bf16x8*)&ksh[(jsub*16 + l15)*64 + (((4+quad) ^ (l15 & 7))*8)];
                    #pragma unroll
                    for (int isub = 0; isub < 2; isub++){
                        f32x4 z = (f32x4){0.f,0.f,0.f,0.f};
                        z = __builtin_amdgcn_mfma_f32_16x16x32_bf16(kf0, qf[isub][0], z, 0, 0, 0);
                        z = __builtin_amdgcn_mfma_f32_16x16x32_bf16(kf1, qf[isub][1], z, 0, 0, 0);
                        sac[jsub][isub] = z;
                    }
                }
                if (jt*64 + 63 > qbase){      // wave-uniform: only diagonal tile
                    #pragma unroll
                    for (int jsub = 0; jsub < 4; jsub++)
                        #pragma unroll
                        for (int r = 0; r < 4; r++){
                            int j = jt*64 + jsub*16 + quad*4 + r;
                            #pragma unroll
                            for (int isub = 0; isub < 2; isub++)
                                if (j > ig[isub]) sac[jsub][isub][r] = -1e30f;
                        }
                }
                // --- exp (fixed max), sum, pack to bf16 ---
                #pragma unroll
                for (int isub = 0; isub < 2; isub++){
                    float rs = 0.f;
                    #pragma unroll
                    for (int jsub = 0; jsub < 4; jsub++){
                        float p0 = __expf(sac[jsub][isub][0]);
                        float p1 = __expf(sac[jsub][isub][1]);
                        float p2 = __expf(sac[jsub][isub][2]);
                        float p3 = __expf(sac[jsub][isub][3]);
                        rs += (p0 + p1) + (p2 + p3);
                        uint2 pk;
                        pk.x = pk2bf(p0, p1);
                        pk.y = pk2bf(p2, p3);
                        *(uint2*)&pwork[wv][isub*16 + l15][jsub*16 + quad*4] = pk;
                    }
                    rs += __shfl_xor(rs, 16, 64);
                    rs += __shfl_xor(rs, 32, 64);
                    lrun[isub] += rs;
                }
                // --- read P as B-operand (same wave, in-order LDS) ---
                bf16x8 pf[2][2];
                #pragma unroll
                for (int kh = 0; kh < 2; kh++)
                    #pragma unroll
                    for (int isub = 0; isub < 2; isub++)
                        pf[kh][isub] = *(const bf16x8*)&pwork[wv][isub*16 + l15][kh*32 + quad*8];
                // --- PV: O^T += V^T * P^T ---
                #pragma unroll
                for (int dsub = 0; dsub < 4; dsub++){
                    bf16x8 vf0 = *(const bf16x8*)&vsh[(dsub*16 + l15)*64 + ((quad     ^ (l15 & 7))*8)];
                    bf16x8 vf1 = *(const bf16x8*)&vsh[(dsub*16 + l15)*64 + (((4+quad) ^ (l15 & 7))*8)];
                    #pragma unroll
                    for (int isub = 0; isub < 2; isub++){
                        oacc[dsub][isub] = __builtin_amdgcn_mfma_f32_16x16x32_bf16(vf0, pf[0][isub], oacc[dsub][isub], 0, 0, 0);
                        oacc[dsub][isub] = __builtin_amdgcn_mfma_f32_16x16x32_bf16(vf1, pf[1][isub], oacc[dsub][isub], 0, 0, 0);
                    }
                }
            }
            __syncthreads();
        }

        // epilogue: normalize, transpose via per-wave LDS, coalesced stores
        float inv[2] = { 1.f / lrun[0], 1.f / lrun[1] };
        #pragma unroll
        for (int dsub = 0; dsub < 4; dsub++)
            #pragma unroll
            for (int isub = 0; isub < 2; isub++){
                uint2 ov;
                ov.x = pk2bf(oacc[dsub][isub][0] * inv[isub], oacc[dsub][isub][1] * inv[isub]);
                ov.y = pk2bf(oacc[dsub][isub][2] * inv[isub], oacc[dsub][isub][3] * inv[isub]);
                *(uint2*)&pwork[wv][isub*16 + l15][dsub*16 + quad*4] = ov;
            }
        #pragma unroll
        for (int rr = 0; rr < 4; rr++){
            int idx = rr*64 + lane;
            int il = idx >> 3, cc = (idx & 7) * 8;
            int t = qb*128 + wv*32 + il;
            *(uint4*)(attnb + (size_t)s*MBT*NC + ((size_t)(b*TSEQ + t))*NC + h*DHEAD + cc) =
                *(const uint4*)&pwork[wv][il][cc];
        }
    }
}

// ---------------------------------------------------------------------------
extern "C" void kernel_launch(void* const* d_in, const int* in_sizes, int n_in,
                              void* d_out, int out_size, void* d_ws, size_t ws_size,
                              hipStream_t stream){
    (void)in_sizes; (void)n_in; (void)out_size; (void)ws_size;
    const float* x     = (const float*)d_in[0];
    const float* noise = (const float*)d_in[1];
    const float* Wk    = (const float*)d_in[2];
    const float* Wv    = (const float*)d_in[3];
    const float* Wq    = (const float*)d_in[4];
    const float* Wo    = (const float*)d_in[5];
    const float* Wg    = (const float*)d_in[6];
    const float* Wn    = (const float*)d_in[7];
    float* out = (float*)d_out;

    char* ws = (char*)d_ws;
    size_t off = 0;
    auto alloc = [&](size_t bytes) -> void* {
        void* p = ws + off;
        off += (bytes + 255) & ~(size_t)255;
        return p;
    };
    unsigned short* xb    = (unsigned short*)alloc((size_t)MBT*NC*2);
    unsigned short* vbufT = (unsigned short*)alloc((size_t)MBT*NC*2);
    unsigned short* kvbuf = (unsigned short*)alloc((size_t)MBT*2048*2);  // K|V, stride 2048
    unsigned short* qselb = (unsigned short*)alloc((size_t)MBT*2*NC*2);  // contiguous after kvbuf
    unsigned short* attnb = (unsigned short*)alloc((size_t)2*MBT*NC*2);
    unsigned short* Wkvt  = (unsigned short*)alloc((size_t)2*NC*NC*2);
    unsigned short* Wqt   = (unsigned short*)alloc((size_t)NEXP*NC*NC*2);
    unsigned short* Wot   = (unsigned short*)alloc((size_t)NEXP*NC*NC*2);
    int*   epair   = (int*)alloc(2*MBT*4);
    float* wpair   = (float*)alloc(2*MBT*4);
    int*   perm    = (int*)alloc(PERM_CAP*4);
    int*   cursor  = (int*)alloc(16*4);
    int*   tile_g  = (int*)alloc(MAXTILES*4);
    int*   tile_pos= (int*)alloc(MAXTILES*4);
    int*   ntiles  = (int*)alloc(4);

    // os[2][MBT][NC] fp32 aliases kvbuf+qselb (both dead after attn; sizes match)
    float* osbuf = (float*)kvbuf;

    prep_w<<<dim3(32,32,18), dim3(32,8), 0, stream>>>(Wk, Wv, Wq, Wo, Wkvt, Wqt, Wot);
    gate_kernel<<<4096, 64, 0, stream>>>(x, noise, Wg, Wn, epair, wpair, xb);
    group_build<<<1, 256, 0, stream>>>(epair, cursor, tile_g, tile_pos, ntiles, perm);
    fill_perm<<<32, 256, 0, stream>>>(epair, cursor, perm);

    gemm_fused<<<1280, 256, 0, stream>>>(xb, Wkvt, Wqt, kvbuf, qselb,
                                         perm, tile_g, tile_pos, ntiles);
    transpose_v<<<dim3(32,32,4), dim3(32,8), 0, stream>>>(kvbuf, vbufT);

    attn_k<<<dim3(4,64,2), 256, 0, stream>>>(qselb, kvbuf, vbufT, attnb);

    gemm_o<<<dim3(8,MAXTILES), 256, 0, stream>>>(attnb, Wot, osbuf, perm, tile_g, tile_pos, ntiles, wpair);
    combine<<<4096, 256, 0, stream>>>(osbuf, out);
}

// Round 7
// 347.035 us; speedup vs baseline: 1.6049x; 1.0495x over previous
//
#include <hip/hip_runtime.h>
#include <hip/hip_bf16.h>

// Problem constants
#define TSEQ   1024
#define NC     1024          // C
#define MBT    4096          // B*T
#define NEXP   8
#define NHEAD  16
#define DHEAD  64
#define PERM_CAP 10240       // 8192 pairs + 16 groups * 128 pad
#define MAXTILES 96

typedef __attribute__((ext_vector_type(8))) short bf16x8;
typedef __attribute__((ext_vector_type(4))) float f32x4;

typedef __attribute__((address_space(3))) unsigned char* lds_ptr_t;
typedef const __attribute__((address_space(1))) unsigned char* glb_ptr_t;

// async global->LDS DMA, 16B per lane, dest = wave-uniform base + lane*16
static __device__ __forceinline__ void gload16(const void* g, void* l){
    __builtin_amdgcn_global_load_lds((glb_ptr_t)g, (lds_ptr_t)l, 16, 0, 0);
}

// RNE fp32->bf16 (values are finite/normal here; no NaN path needed)
static __device__ __forceinline__ unsigned short f2bf(float x){
    unsigned int u = __float_as_uint(x);
    u += 0x7fff + ((u >> 16) & 1);
    return (unsigned short)(u >> 16);
}
static __device__ __forceinline__ unsigned int pk2bf(float a, float b){
    unsigned int ua = __float_as_uint(a), ub = __float_as_uint(b);
    ua += 0x7fff + ((ua >> 16) & 1);
    ub += 0x7fff + ((ub >> 16) & 1);
    return (ua >> 16) | (ub & 0xffff0000u);
}
static __device__ __forceinline__ float bf2f(unsigned short u){
    return __uint_as_float(((unsigned int)u) << 16);
}

// ---------------------------------------------------------------------------
// Gate: logits, top2, softmax(2).  Emits xb = bf16(x).  4 tokens per block.
// ---------------------------------------------------------------------------
__global__ __launch_bounds__(256)
void gate_kernel(const float* __restrict__ x, const float* __restrict__ noise,
                 const float* __restrict__ Wg, const float* __restrict__ Wn,
                 int* __restrict__ epair, float* __restrict__ wpair,
                 unsigned short* __restrict__ xb){
    int t = blockIdx.x*4 + (threadIdx.x >> 6);
    int lane = threadIdx.x & 63;
    float ag[8] = {0,0,0,0,0,0,0,0};
    float an[8] = {0,0,0,0,0,0,0,0};
    const float* xr = x + (size_t)t * NC;
    unsigned short* xbr = xb + (size_t)t * NC;
    for (int c = lane; c < NC; c += 64){
        float xv = xr[c];
        xbr[c] = f2bf(xv);
        #pragma unroll
        for (int j = 0; j < 8; j++){
            ag[j] = fmaf(xv, Wg[c*8 + j], ag[j]);
            an[j] = fmaf(xv, Wn[c*8 + j], an[j]);
        }
    }
    #pragma unroll
    for (int j = 0; j < 8; j++){
        #pragma unroll
        for (int o = 32; o >= 1; o >>= 1){
            ag[j] += __shfl_xor(ag[j], o, 64);
            an[j] += __shfl_xor(an[j], o, 64);
        }
    }
    if (lane == 0){
        float lg[8];
        #pragma unroll
        for (int j = 0; j < 8; j++){
            float z = an[j];
            float sp = (z > 20.f) ? z : log1pf(expf(z));
            lg[j] = ag[j] + noise[(size_t)t*8 + j] * sp;
        }
        int i0 = 0; float v0 = lg[0];
        #pragma unroll
        for (int j = 1; j < 8; j++) if (lg[j] > v0){ v0 = lg[j]; i0 = j; }
        int i1 = -1; float v1 = -3.4e38f;
        #pragma unroll
        for (int j = 0; j < 8; j++) if (j != i0 && lg[j] > v1){ v1 = lg[j]; i1 = j; }
        float e1 = expf(v1 - v0);
        float w0 = 1.f / (1.f + e1);
        epair[2*t]   = i0;
        epair[2*t+1] = i1;
        wpair[2*t]   = w0;
        wpair[2*t+1] = e1 * w0;
    }
}

// ---------------------------------------------------------------------------
// All 18 weight transposes (Wk, Wv, 8xWq, 8xWo) in ONE launch.  z selects.
// ---------------------------------------------------------------------------
__global__ void prep_w(const float* __restrict__ Wk, const float* __restrict__ Wv,
                       const float* __restrict__ Wq, const float* __restrict__ Wo,
                       unsigned short* __restrict__ Wkvt, unsigned short* __restrict__ Wqt,
                       unsigned short* __restrict__ Wot){
    __shared__ float t[32][33];
    int z = blockIdx.z;
    const float* src; unsigned short* dst;
    if (z == 0){ src = Wk; dst = Wkvt; }
    else if (z == 1){ src = Wv; dst = Wkvt + (size_t)NC*NC; }
    else if (z < 10){ src = Wq + (size_t)(z-2)*NC*NC; dst = Wqt + (size_t)(z-2)*NC*NC; }
    else { src = Wo + (size_t)(z-10)*NC*NC; dst = Wot + (size_t)(z-10)*NC*NC; }
    int k0 = blockIdx.x * 32, n0 = blockIdx.y * 32;
    int tx = threadIdx.x, ty = threadIdx.y;
    #pragma unroll
    for (int i = 0; i < 4; i++)
        t[ty + i*8][tx] = src[(size_t)(k0 + ty + i*8)*NC + n0 + tx];
    __syncthreads();
    #pragma unroll
    for (int i = 0; i < 4; i++)
        dst[(size_t)(n0 + ty + i*8)*NC + k0 + tx] = f2bf(t[tx][ty + i*8]);
}

// ---------------------------------------------------------------------------
// Grouping
// ---------------------------------------------------------------------------
__global__ void group_build(const int* __restrict__ epair, int* __restrict__ cursor,
                            int* __restrict__ tile_g, int* __restrict__ tile_pos,
                            int* __restrict__ ntiles, int* __restrict__ perm){
    __shared__ int cnt[16];
    int tid = threadIdx.x;
    if (tid < 16) cnt[tid] = 0;
    __syncthreads();
    for (int p = tid; p < 2*MBT; p += 256){
        int g = ((p & 1) << 3) | epair[p];
        atomicAdd(&cnt[g], 1);
    }
    for (int i = tid; i < PERM_CAP; i += 256) perm[i] = -1;
    __syncthreads();
    if (tid == 0){
        int off = 0, tt = 0;
        for (int g = 0; g < 16; g++){
            int c = cnt[g];
            cursor[g] = off;
            int nt = (c + 127) >> 7;
            for (int i = 0; i < nt; i++){ tile_g[tt] = g; tile_pos[tt] = off + i*128; tt++; }
            off += nt << 7;
        }
        ntiles[0] = tt;
    }
}

// wave-aggregated scatter: one atomic per (wave, group) instead of per thread
__global__ __launch_bounds__(256)
void fill_perm(const int* __restrict__ epair, int* __restrict__ cursor,
               int* __restrict__ perm){
    int p = blockIdx.x * 256 + threadIdx.x;      // 32 blocks x 256 = 8192
    int lane = threadIdx.x & 63;
    int g = ((p & 1) << 3) | epair[p];
    unsigned long long ltmask = (lane == 63) ? 0x7fffffffffffffffull
                                             : (((unsigned long long)1 << lane) - 1);
    #pragma unroll 1
    for (int grp = 0; grp < 16; grp++){
        unsigned long long m = __ballot(g == grp);
        if (m == 0ull) continue;
        if (g == grp){
            int leader = __ffsll(m) - 1;
            int base = 0;
            if (lane == leader) base = atomicAdd(&cursor[grp], __popcll(m));
            base = __shfl(base, leader, 64);
            perm[base + __popcll(m & ltmask)] = p;
        }
    }
}

// ---------------------------------------------------------------------------
// Fused KV + Q GEMM.  Blocks [0,512): KV (N=2048: ntile<8 -> K rows into kbuf,
// ntile>=8 -> V written TRANSPOSED into vbufT).  Blocks [512,1280): grouped Q.
// 128x128 tile, BK=64, global_load_lds + XOR swizzle, LDS-bounce epilogues.
// ---------------------------------------------------------------------------
__global__ __launch_bounds__(256)
void gemm_fused(const unsigned short* __restrict__ xb,
                const unsigned short* __restrict__ Wkvt,
                const unsigned short* __restrict__ Wqt,
                unsigned short* __restrict__ kbuf,
                unsigned short* __restrict__ vbT,
                unsigned short* __restrict__ qselb,
                const int* __restrict__ perm,
                const int* __restrict__ tile_g,
                const int* __restrict__ tile_pos,
                const int* __restrict__ ntiles){
    int flat = blockIdx.x;
    bool isQ = (flat >= 512);
    int ntile, slot, tpos = 0;
    const unsigned short* bt;
    if (!isQ){
        ntile = flat & 15; slot = flat >> 4;
        bt = Wkvt;
    } else {
        int f2 = flat - 512;
        ntile = f2 & 7; slot = f2 >> 3;
        if (slot >= ntiles[0]) return;
        int g = tile_g[slot];
        bt = Wqt + (size_t)(g & 7) * NC * NC;
        tpos = tile_pos[slot];
    }

    __shared__ __align__(16) unsigned short smem[16896];   // staging 16384 / bounce 128*132
    unsigned short* As = smem;
    unsigned short* Bs = smem + 8192;

    int tid = threadIdx.x;
    int lane = tid & 63, wv = tid >> 6;
    int wr = wv >> 1, wc = wv & 1;
    int quad = lane >> 4, l15 = lane & 15;

    int laneR = lane >> 3;
    int swz = ((lane & 7) ^ (laneR & 7)) * 8;

    const unsigned short* ag[4];
    const unsigned short* bg[4];
    #pragma unroll
    for (int it = 0; it < 4; it++){
        int row = wv*32 + it*8 + laneR;
        if (!isQ){
            ag[it] = xb + (size_t)(slot*128 + row) * NC + swz;
        } else {
            int p = perm[tpos + row];
            if (p < 0) p = 0;                // harmless: C row discarded at store
            ag[it] = xb + (size_t)(p >> 1) * NC + swz;
        }
        bg[it] = bt + (size_t)(ntile*128 + row) * NC + swz;
    }

    f32x4 acc[4][4];
    #pragma unroll
    for (int i = 0; i < 4; i++)
        #pragma unroll
        for (int j = 0; j < 4; j++) acc[i][j] = (f32x4){0.f,0.f,0.f,0.f};

    for (int kk = 0; kk < NC; kk += 64){
        #pragma unroll
        for (int it = 0; it < 4; it++){
            gload16(ag[it] + kk, &As[(wv*32 + it*8)*64]);
            gload16(bg[it] + kk, &Bs[(wv*32 + it*8)*64]);
        }
        __syncthreads();
        #pragma unroll
        for (int kh = 0; kh < 2; kh++){
            bf16x8 af[4], bfr[4];
            #pragma unroll
            for (int mi = 0; mi < 4; mi++)
                af[mi]  = *(const bf16x8*)&As[(wr*64 + mi*16 + l15)*64 + (((kh*4 + quad) ^ (l15 & 7))*8)];
            #pragma unroll
            for (int ni = 0; ni < 4; ni++)
                bfr[ni] = *(const bf16x8*)&Bs[(wc*64 + ni*16 + l15)*64 + (((kh*4 + quad) ^ (l15 & 7))*8)];
            #pragma unroll
            for (int mi = 0; mi < 4; mi++)
                #pragma unroll
                for (int ni = 0; ni < 4; ni++)
                    acc[mi][ni] = __builtin_amdgcn_mfma_f32_16x16x32_bf16(af[mi], bfr[ni], acc[mi][ni], 0, 0, 0);
        }
        __syncthreads();
    }

    bool isV = (!isQ) && (ntile >= 8);
    float scale = isQ ? 0.125f : 1.0f;
    if (!isV){
        // row-major bounce: Cs[m][n], stride 132
        #pragma unroll
        for (int mi = 0; mi < 4; mi++)
            #pragma unroll
            for (int ni = 0; ni < 4; ni++)
                #pragma unroll
                for (int r = 0; r < 4; r++)
                    smem[(wr*64 + mi*16 + quad*4 + r)*132 + wc*64 + ni*16 + l15] =
                        f2bf(scale * acc[mi][ni][r]);
        __syncthreads();
        #pragma unroll
        for (int cc = 0; cc < 8; cc++){
            int chunk = tid + cc*256;           // 0..2047
            int row = chunk >> 4, c8 = (chunk & 15) * 8;
            uint4 v = *(const uint4*)&smem[row*132 + c8];
            if (!isQ){
                *(uint4*)(kbuf + (size_t)(slot*128 + row)*NC + ntile*128 + c8) = v;
            } else {
                int p = perm[tpos + row];
                if (p >= 0)
                    *(uint4*)(qselb + (size_t)p*NC + ntile*128 + c8) = v;
            }
        }
    } else {
        // transposed bounce: Cs[c][t], stride 132; acc rows (consecutive m) -> ushort4
        #pragma unroll
        for (int mi = 0; mi < 4; mi++)
            #pragma unroll
            for (int ni = 0; ni < 4; ni++){
                ushort4 pk;
                pk.x = f2bf(acc[mi][ni][0]);
                pk.y = f2bf(acc[mi][ni][1]);
                pk.z = f2bf(acc[mi][ni][2]);
                pk.w = f2bf(acc[mi][ni][3]);
                *(ushort4*)&smem[(wc*64 + ni*16 + l15)*132 + wr*64 + mi*16 + quad*4] = pk;
            }
        __syncthreads();
        int b = slot >> 3, t0 = (slot & 7)*128;
        int cvBase = (ntile - 8)*128;
        #pragma unroll
        for (int cc = 0; cc < 8; cc++){
            int chunk = tid + cc*256;           // 0..2047
            int row = chunk >> 4, c8 = (chunk & 15) * 8;  // row = local c, c8 = t offset
            uint4 v = *(const uint4*)&smem[row*132 + c8];
            *(uint4*)(vbT + ((size_t)(b*NC + cvBase + row))*TSEQ + t0 + c8) = v;
        }
    }
}

// ---------------------------------------------------------------------------
// O-projection GEMM (grouped): stores RAW bf16 acc into os[p&1][t][c]
// (weight applied in combine).  LDS-bounce epilogue.
// ---------------------------------------------------------------------------
__global__ __launch_bounds__(256)
void gemm_o(const unsigned short* __restrict__ A,
            const unsigned short* __restrict__ Bt,
            unsigned short* __restrict__ osb,
            const int* __restrict__ perm,
            const int* __restrict__ tile_g,
            const int* __restrict__ tile_pos,
            const int* __restrict__ ntiles){
    int ntile = blockIdx.x;
    int slot  = blockIdx.y;
    if (slot >= ntiles[0]) return;
    int g = tile_g[slot];
    const unsigned short* bt = Bt + (size_t)(g & 7) * NC * NC;
    int tpos = tile_pos[slot];

    __shared__ __align__(16) unsigned short smem[16896];
    unsigned short* As = smem;
    unsigned short* Bs = smem + 8192;

    int tid = threadIdx.x;
    int lane = tid & 63, wv = tid >> 6;
    int wr = wv >> 1, wc = wv & 1;
    int quad = lane >> 4, l15 = lane & 15;

    int laneR = lane >> 3;
    int swz = ((lane & 7) ^ (laneR & 7)) * 8;

    const unsigned short* ag[4];
    const unsigned short* bg[4];
    #pragma unroll
    for (int it = 0; it < 4; it++){
        int row = wv*32 + it*8 + laneR;
        int p = perm[tpos + row];
        if (p < 0) p = 0;
        ag[it] = A + (size_t)(p & 1) * MBT * NC + (size_t)(p >> 1) * NC + swz;
        bg[it] = bt + (size_t)(ntile*128 + row) * NC + swz;
    }

    f32x4 acc[4][4];
    #pragma unroll
    for (int i = 0; i < 4; i++)
        #pragma unroll
        for (int j = 0; j < 4; j++) acc[i][j] = (f32x4){0.f,0.f,0.f,0.f};

    for (int kk = 0; kk < NC; kk += 64){
        #pragma unroll
        for (int it = 0; it < 4; it++){
            gload16(ag[it] + kk, &As[(wv*32 + it*8)*64]);
            gload16(bg[it] + kk, &Bs[(wv*32 + it*8)*64]);
        }
        __syncthreads();
        #pragma unroll
        for (int kh = 0; kh < 2; kh++){
            bf16x8 af[4], bfr[4];
            #pragma unroll
            for (int mi = 0; mi < 4; mi++)
                af[mi]  = *(const bf16x8*)&As[(wr*64 + mi*16 + l15)*64 + (((kh*4 + quad) ^ (l15 & 7))*8)];
            #pragma unroll
            for (int ni = 0; ni < 4; ni++)
                bfr[ni] = *(const bf16x8*)&Bs[(wc*64 + ni*16 + l15)*64 + (((kh*4 + quad) ^ (l15 & 7))*8)];
            #pragma unroll
            for (int mi = 0; mi < 4; mi++)
                #pragma unroll
                for (int ni = 0; ni < 4; ni++)
                    acc[mi][ni] = __builtin_amdgcn_mfma_f32_16x16x32_bf16(af[mi], bfr[ni], acc[mi][ni], 0, 0, 0);
        }
        __syncthreads();
    }

    #pragma unroll
    for (int mi = 0; mi < 4; mi++)
        #pragma unroll
        for (int ni = 0; ni < 4; ni++)
            #pragma unroll
            for (int r = 0; r < 4; r++)
                smem[(wr*64 + mi*16 + quad*4 + r)*132 + wc*64 + ni*16 + l15] =
                    f2bf(acc[mi][ni][r]);
    __syncthreads();
    #pragma unroll
    for (int cc = 0; cc < 8; cc++){
        int chunk = tid + cc*256;               // 0..2047
        int row = chunk >> 4, c8 = (chunk & 15) * 8;
        int p = perm[tpos + row];
        if (p >= 0){
            uint4 v = *(const uint4*)&smem[row*132 + c8];
            *(uint4*)(osb + ((size_t)(p & 1)*MBT + (p >> 1))*NC + ntile*128 + c8) = v;
        }
    }
}

// out[t][c] = w0[t]*os0[t][c] + w1[t]*os1[t][c]   (os bf16, out fp32)
__global__ __launch_bounds__(256)
void combine(const unsigned short* __restrict__ os, const float* __restrict__ wpair,
             float* __restrict__ out){
    size_t flat = ((size_t)blockIdx.x * 256 + threadIdx.x) * 8;
    int t = (int)(flat >> 10);
    float w0 = wpair[2*t], w1 = wpair[2*t+1];
    bf16x8 a = *(const bf16x8*)(os + flat);
    bf16x8 b = *(const bf16x8*)(os + (size_t)MBT*NC + flat);
    float4 r0, r1;
    r0.x = w0*bf2f((unsigned short)a[0]) + w1*bf2f((unsigned short)b[0]);
    r0.y = w0*bf2f((unsigned short)a[1]) + w1*bf2f((unsigned short)b[1]);
    r0.z = w0*bf2f((unsigned short)a[2]) + w1*bf2f((unsigned short)b[2]);
    r0.w = w0*bf2f((unsigned short)a[3]) + w1*bf2f((unsigned short)b[3]);
    r1.x = w0*bf2f((unsigned short)a[4]) + w1*bf2f((unsigned short)b[4]);
    r1.y = w0*bf2f((unsigned short)a[5]) + w1*bf2f((unsigned short)b[5]);
    r1.z = w0*bf2f((unsigned short)a[6]) + w1*bf2f((unsigned short)b[6]);
    r1.w = w0*bf2f((unsigned short)a[7]) + w1*bf2f((unsigned short)b[7]);
    *(float4*)(out + flat)     = r0;
    *(float4*)(out + flat + 4) = r1;
}

// ---------------------------------------------------------------------------
// Flash attention: fixed-max softmax, wave-uniform mask, packed bf16, DMA
// staging + XOR swizzle.  Block = (qpair, b*16+h, s), qb pairing for balance.
// ---------------------------------------------------------------------------
__global__ __launch_bounds__(256)
void attn_k(const unsigned short* __restrict__ qsel, const unsigned short* __restrict__ kb,
            const unsigned short* __restrict__ vbT, unsigned short* __restrict__ attnb){
    int b = blockIdx.y >> 4, h = blockIdx.y & 15;
    int s = blockIdx.z;
    int tid = threadIdx.x, lane = tid & 63, wv = tid >> 6;
    int quad = lane >> 4, l15 = lane & 15;
    int laneR = lane >> 3;
    int swz = ((lane & 7) ^ (laneR & 7)) * 8;

    __shared__ __align__(16) unsigned short ksh[64*64];
    __shared__ __align__(16) unsigned short vsh[64*64];
    __shared__ __align__(16) unsigned short pwork[4][32][72];

    #pragma unroll
    for (int half = 0; half < 2; half++){
        int qb = half ? (7 - blockIdx.x) : blockIdx.x;
        int qbase = qb*128 + wv*32;
        int ig[2] = { qbase + l15, qbase + 16 + l15 };

        bf16x8 qf[2][2];
        #pragma unroll
        for (int isub = 0; isub < 2; isub++){
            const unsigned short* qrow = qsel + (((size_t)(b*TSEQ + qbase + isub*16 + l15))*2 + s)*NC + h*DHEAD;
            qf[isub][0] = *(const bf16x8*)(qrow + quad*8);
            qf[isub][1] = *(const bf16x8*)(qrow + 32 + quad*8);
        }

        float lrun[2] = {0.f, 0.f};
        f32x4 oacc[4][2];
        #pragma unroll
        for (int d = 0; d < 4; d++)
            #pragma unroll
            for (int i = 0; i < 2; i++) oacc[d][i] = (f32x4){0.f,0.f,0.f,0.f};

        int njt = qb*2 + 2;
        for (int jt = 0; jt < njt; jt++){
            #pragma unroll
            for (int it = 0; it < 2; it++){
                int r = wv*16 + it*8 + laneR;
                gload16(kb  + ((size_t)(b*TSEQ + jt*64 + r))*NC + h*DHEAD + swz,
                        &ksh[(wv*16 + it*8)*64]);
                gload16(vbT + ((size_t)(b*NC + h*DHEAD + r))*TSEQ + jt*64 + swz,
                        &vsh[(wv*16 + it*8)*64]);
            }
            __syncthreads();

            if (jt*64 <= qbase + 31){
                // --- QK^T (S^T orientation); q pre-scaled by 1/8 ---
                f32x4 sac[4][2];
                #pragma unroll
                for (int jsub = 0; jsub < 4; jsub++){
                    bf16x8 kf0 = *(const bf16x8*)&ksh[(jsub*16 + l15)*64 + ((quad     ^ (l15 & 7))*8)];
                    bf16x8 kf1 = *(const bf16x8*)&ksh[(jsub*16 + l15)*64 + (((4+quad) ^ (l15 & 7))*8)];
                    #pragma unroll
                    for (int isub = 0; isub < 2; isub++){
                        f32x4 z = (f32x4){0.f,0.f,0.f,0.f};
                        z = __builtin_amdgcn_mfma_f32_16x16x32_bf16(kf0, qf[isub][0], z, 0, 0, 0);
                        z = __builtin_amdgcn_mfma_f32_16x16x32_bf16(kf1, qf[isub][1], z, 0, 0, 0);
                        sac[jsub][isub] = z;
                    }
                }
                if (jt*64 + 63 > qbase){      // wave-uniform: only diagonal tiles
                    #pragma unroll
                    for (int jsub = 0; jsub < 4; jsub++)
                        #pragma unroll
                        for (int r = 0; r < 4; r++){
                            int j = jt*64 + jsub*16 + quad*4 + r;
                            #pragma unroll
                            for (int isub = 0; isub < 2; isub++)
                                if (j > ig[isub]) sac[jsub][isub][r] = -1e30f;
                        }
                }
                // --- exp (fixed max), sum, pack to bf16 ---
                #pragma unroll
                for (int isub = 0; isub < 2; isub++){
                    float rs = 0.f;
                    #pragma unroll
                    for (int jsub = 0; jsub < 4; jsub++){
                        float p0 = __expf(sac[jsub][isub][0]);
                        float p1 = __expf(sac[jsub][isub][1]);
                        float p2 = __expf(sac[jsub][isub][2]);
                        float p3 = __expf(sac[jsub][isub][3]);
                        rs += (p0 + p1) + (p2 + p3);
                        uint2 pk;
                        pk.x = pk2bf(p0, p1);
                        pk.y = pk2bf(p2, p3);
                        *(uint2*)&pwork[wv][isub*16 + l15][jsub*16 + quad*4] = pk;
                    }
                    rs += __shfl_xor(rs, 16, 64);
                    rs += __shfl_xor(rs, 32, 64);
                    lrun[isub] += rs;
                }
                // --- read P as B-operand (same wave, in-order LDS) ---
                bf16x8 pf[2][2];
                #pragma unroll
                for (int kh = 0; kh < 2; kh++)
                    #pragma unroll
                    for (int isub = 0; isub < 2; isub++)
                        pf[kh][isub] = *(const bf16x8*)&pwork[wv][isub*16 + l15][kh*32 + quad*8];
                // --- PV: O^T += V^T * P^T ---
                #pragma unroll
                for (int dsub = 0; dsub < 4; dsub++){
                    bf16x8 vf0 = *(const bf16x8*)&vsh[(dsub*16 + l15)*64 + ((quad     ^ (l15 & 7))*8)];
                    bf16x8 vf1 = *(const bf16x8*)&vsh[(dsub*16 + l15)*64 + (((4+quad) ^ (l15 & 7))*8)];
                    #pragma unroll
                    for (int isub = 0; isub < 2; isub++){
                        oacc[dsub][isub] = __builtin_amdgcn_mfma_f32_16x16x32_bf16(vf0, pf[0][isub], oacc[dsub][isub], 0, 0, 0);
                        oacc[dsub][isub] = __builtin_amdgcn_mfma_f32_16x16x32_bf16(vf1, pf[1][isub], oacc[dsub][isub], 0, 0, 0);
                    }
                }
            }
            __syncthreads();
        }

        // epilogue: normalize, transpose via per-wave LDS, coalesced stores
        float inv[2] = { 1.f / lrun[0], 1.f / lrun[1] };
        #pragma unroll
        for (int dsub = 0; dsub < 4; dsub++)
            #pragma unroll
            for (int isub = 0; isub < 2; isub++){
                uint2 ov;
                ov.x = pk2bf(oacc[dsub][isub][0] * inv[isub], oacc[dsub][isub][1] * inv[isub]);
                ov.y = pk2bf(oacc[dsub][isub][2] * inv[isub], oacc[dsub][isub][3] * inv[isub]);
                *(uint2*)&pwork[wv][isub*16 + l15][dsub*16 + quad*4] = ov;
            }
        #pragma unroll
        for (int rr = 0; rr < 4; rr++){
            int idx = rr*64 + lane;
            int il = idx >> 3, cc = (idx & 7) * 8;
            int t = qb*128 + wv*32 + il;
            *(uint4*)(attnb + (size_t)s*MBT*NC + ((size_t)(b*TSEQ + t))*NC + h*DHEAD + cc) =
                *(const uint4*)&pwork[wv][il][cc];
        }
    }
}

// ---------------------------------------------------------------------------
extern "C" void kernel_launch(void* const* d_in, const int* in_sizes, int n_in,
                              void* d_out, int out_size, void* d_ws, size_t ws_size,
                              hipStream_t stream){
    (void)in_sizes; (void)n_in; (void)out_size; (void)ws_size;
    const float* x     = (const float*)d_in[0];
    const float* noise = (const float*)d_in[1];
    const float* Wk    = (const float*)d_in[2];
    const float* Wv    = (const float*)d_in[3];
    const float* Wq    = (const float*)d_in[4];
    const float* Wo    = (const float*)d_in[5];
    const float* Wg    = (const float*)d_in[6];
    const float* Wn    = (const float*)d_in[7];
    float* out = (float*)d_out;

    char* ws = (char*)d_ws;
    size_t off = 0;
    auto alloc = [&](size_t bytes) -> void* {
        void* p = ws + off;
        off += (bytes + 255) & ~(size_t)255;
        return p;
    };
    unsigned short* xb    = (unsigned short*)alloc((size_t)MBT*NC*2);
    unsigned short* vbufT = (unsigned short*)alloc((size_t)MBT*NC*2);
    unsigned short* kbuf  = (unsigned short*)alloc((size_t)MBT*NC*2);
    unsigned short* qselb = (unsigned short*)alloc((size_t)MBT*2*NC*2);
    unsigned short* attnb = (unsigned short*)alloc((size_t)2*MBT*NC*2);
    unsigned short* Wkvt  = (unsigned short*)alloc((size_t)2*NC*NC*2);
    unsigned short* Wqt   = (unsigned short*)alloc((size_t)NEXP*NC*NC*2);
    unsigned short* Wot   = (unsigned short*)alloc((size_t)NEXP*NC*NC*2);
    int*   epair   = (int*)alloc(2*MBT*4);
    float* wpair   = (float*)alloc(2*MBT*4);
    int*   perm    = (int*)alloc(PERM_CAP*4);
    int*   cursor  = (int*)alloc(16*4);
    int*   tile_g  = (int*)alloc(MAXTILES*4);
    int*   tile_pos= (int*)alloc(MAXTILES*4);
    int*   ntiles  = (int*)alloc(4);

    // os[2][MBT][NC] bf16 aliases qselb (dead after attn; same size)
    unsigned short* osb = qselb;

    prep_w<<<dim3(32,32,18), dim3(32,8), 0, stream>>>(Wk, Wv, Wq, Wo, Wkvt, Wqt, Wot);
    gate_kernel<<<1024, 256, 0, stream>>>(x, noise, Wg, Wn, epair, wpair, xb);
    group_build<<<1, 256, 0, stream>>>(epair, cursor, tile_g, tile_pos, ntiles, perm);
    fill_perm<<<32, 256, 0, stream>>>(epair, cursor, perm);

    gemm_fused<<<1280, 256, 0, stream>>>(xb, Wkvt, Wqt, kbuf, vbufT, qselb,
                                         perm, tile_g, tile_pos, ntiles);

    attn_k<<<dim3(4,64,2), 256, 0, stream>>>(qselb, kbuf, vbufT, attnb);

    gemm_o<<<dim3(8,MAXTILES), 256, 0, stream>>>(attnb, Wot, osb, perm, tile_g, tile_pos, ntiles);
    combine<<<2048, 256, 0, stream>>>(osb, wpair, out);
}